// Round 5
// baseline (49432.950 us; speedup 1.0000x reference)
//
#include <hip/hip_runtime.h>
#include <hip/hip_bf16.h>

#define EMBD 300
#define GG   4096
#define NLAY 5
#define KP1  320   // padded K for EMB=300 inputs
#define KP2  640   // padded K for 2*EMB=600 inputs
#define NP1  640   // padded B-rows / out-cols for 600
#define NP2  320   // padded B-rows for 300-col GEMM2 (multiple of 64)

typedef unsigned short ushort_t;
typedef short short8 __attribute__((ext_vector_type(8)));
typedef short short4v __attribute__((ext_vector_type(4)));
typedef float f32x4 __attribute__((ext_vector_type(4)));

static inline int cdiv(int a, int b) { return (a + b - 1) / b; }

// ---------------- helpers ----------------

__device__ inline void dma16(const ushort_t* g, ushort_t* l) {
    __builtin_amdgcn_global_load_lds(
        (const __attribute__((address_space(1))) unsigned int*)g,
        (__attribute__((address_space(3))) unsigned int*)l, 16, 0, 0);
}

__device__ inline void bf16_split(float v, ushort_t& h, ushort_t& l) {
    union { __hip_bfloat16 b; ushort_t u; } c;
    c.b = __float2bfloat16(v);
    h = c.u;
    float hf = __bfloat162float(c.b);
    c.b = __float2bfloat16(v - hf);
    l = c.u;
}

// ---------------- elementwise kernels ----------------

__global__ void atom_encode4(const int* __restrict__ x, const float* __restrict__ aemb,
                             float* __restrict__ h, int N) {
    int i = blockIdx.x * blockDim.x + threadIdx.x;
    int total = N * 75;
    if (i >= total) return;
    int n = i / 75, d4 = i - n * 75;
    const int* xr = x + n * 9;
    float4 s = make_float4(0.f, 0.f, 0.f, 0.f);
    const float4* a4 = (const float4*)aemb;
#pragma unroll
    for (int f = 0; f < 9; ++f) {
        float4 v = a4[(size_t)((f << 7) + xr[f]) * 75 + d4];
        s.x += v.x; s.y += v.y; s.z += v.z; s.w += v.w;
    }
    ((float4*)h)[i] = s;
}

__global__ void init_vn4(const float* __restrict__ vn_emb, float* __restrict__ vn) {
    int i = blockIdx.x * blockDim.x + threadIdx.x;
    if (i >= GG * 75) return;
    ((float4*)vn)[i] = ((const float4*)vn_emb)[i % 75];
}

__global__ void find_starts(const int* __restrict__ batch, int* __restrict__ starts, int N) {
    int g = blockIdx.x * blockDim.x + threadIdx.x;
    if (g > GG) return;
    int lo = 0, hi = N;
    while (lo < hi) {
        int mid = (lo + hi) >> 1;
        if (batch[mid] < g) lo = mid + 1; else hi = mid;
    }
    starts[g] = lo;
}

// h += vn[batch]  (in place)
__global__ void prep_vn(float* __restrict__ h, const float* __restrict__ vn,
                        const int* __restrict__ batch, int N) {
    int i = blockIdx.x * blockDim.x + threadIdx.x;
    int total = N * 75;
    if (i >= total) return;
    int n = i / 75, d4 = i - n * 75;
    float4 hv = ((const float4*)h)[i];
    float4 vv = ((const float4*)vn)[(size_t)batch[n] * 75 + d4];
    hv.x += vv.x; hv.y += vv.y; hv.z += vv.z; hv.w += vv.w;
    ((float4*)h)[i] = hv;
}

__global__ void pool_graphs(const float* __restrict__ h, const int* __restrict__ starts,
                            float* __restrict__ pooled) {
    int g = blockIdx.x;
    int t = threadIdx.x;
    if (t >= EMBD) return;
    int s0 = starts[g], s1 = starts[g + 1];
    float s = 0.f;
    for (int n = s0; n < s1; ++n) s += h[(size_t)n * EMBD + t];
    pooled[(size_t)g * EMBD + t] = s;
}

__global__ void pool_mean(const float* __restrict__ h, const int* __restrict__ starts,
                          float* __restrict__ out) {
    int g = blockIdx.x;
    int t = threadIdx.x;
    if (t >= EMBD) return;
    int s0 = starts[g], s1 = starts[g + 1];
    float s = 0.f;
    for (int n = s0; n < s1; ++n) s += h[(size_t)n * EMBD + t];
    float cnt = (float)(s1 - s0);
    out[(size_t)g * EMBD + t] = s / fmaxf(cnt, 1.0f);
}

// ---------------- edge bucket sort (once per launch) ----------------

__global__ void ecount(const int* __restrict__ ei, int* __restrict__ cnt, int E) {
    int e = blockIdx.x * blockDim.x + threadIdx.x;
    if (e >= E) return;
    atomicAdd(&cnt[ei[E + e]], 1);
}

__global__ void scan_counts(const int* __restrict__ cnt, int* __restrict__ estart,
                            int* __restrict__ cursor, int N, int E) {
    __shared__ int part[1024];
    int tid = threadIdx.x;
    int vpt = (N + 1023) >> 10;
    int lo = tid * vpt, hi = lo + vpt;
    if (hi > N) hi = N;
    int s = 0;
    for (int j = lo; j < hi; ++j) s += cnt[j];
    part[tid] = s;
    __syncthreads();
    for (int d = 1; d < 1024; d <<= 1) {
        int v = (tid >= d) ? part[tid - d] : 0;
        __syncthreads();
        part[tid] += v;
        __syncthreads();
    }
    int run = part[tid] - s;
    for (int j = lo; j < hi; ++j) { estart[j] = run; cursor[j] = run; run += cnt[j]; }
    if (tid == 0) estart[N] = E;
}

__global__ void escatter(const int* __restrict__ ei, int* __restrict__ cursor,
                         int* __restrict__ ebucket, int E) {
    int e = blockIdx.x * blockDim.x + threadIdx.x;
    if (e >= E) return;
    int c = ei[E + e];
    int p = atomicAdd(&cursor[c], 1);
    ebucket[p] = e;
}

// ---------------- fused aggregate: (1+eps)h + sum relu(h[row]+bond) -> split bf16 ----------------
#define NPB 4   // nodes per block; blockDim = NPB*80 = 320

__global__ void aggregate(const float* __restrict__ h, const int* __restrict__ ei,
                          const int* __restrict__ ea, const float* __restrict__ bemb,
                          const int* __restrict__ estart, const int* __restrict__ ebucket,
                          const float* __restrict__ epsp,
                          ushort_t* __restrict__ aggH, ushort_t* __restrict__ aggL,
                          int N, int E) {
    int n = blockIdx.x * NPB + threadIdx.x / 80;
    int slot = threadIdx.x % 80;
    if (n >= N) return;
    float4 acc = make_float4(0.f, 0.f, 0.f, 0.f);
    if (slot < 75) {
        const float4* h4 = (const float4*)h;
        const float4* b4 = (const float4*)bemb;
        float ce = 1.0f + *epsp;
        float4 hv = h4[(size_t)n * 75 + slot];
        acc = make_float4(ce * hv.x, ce * hv.y, ce * hv.z, ce * hv.w);
        int p0 = estart[n], p1 = estart[n + 1];
        for (int p = p0; p < p1; ++p) {
            int e = ebucket[p];
            int r = ei[e];
            int a0 = ea[3 * e], a1 = ea[3 * e + 1], a2 = ea[3 * e + 2];
            float4 xv = h4[(size_t)r * 75 + slot];
            float4 e0 = b4[(size_t)a0 * 75 + slot];
            float4 e1 = b4[(size_t)(8 + a1) * 75 + slot];
            float4 e2 = b4[(size_t)(16 + a2) * 75 + slot];
            acc.x += fmaxf(xv.x + e0.x + e1.x + e2.x, 0.f);
            acc.y += fmaxf(xv.y + e0.y + e1.y + e2.y, 0.f);
            acc.z += fmaxf(xv.z + e0.z + e1.z + e2.z, 0.f);
            acc.w += fmaxf(xv.w + e0.w + e1.w + e2.w, 0.f);
        }
    }
    float vals[4] = {acc.x, acc.y, acc.z, acc.w};
    short4v hv4, lv4;
#pragma unroll
    for (int j = 0; j < 4; ++j) {
        ushort_t hh, ll;
        bf16_split(vals[j], hh, ll);
        hv4[j] = (short)hh;
        lv4[j] = (short)ll;
    }
    size_t o = (size_t)n * KP1 + slot * 4;
    *(short4v*)(aggH + o) = hv4;
    *(short4v*)(aggL + o) = lv4;
}

// ---------------- split / transpose kernels ----------------

// in [M][Kreal] fp32 (+optional add2) -> H,L ushort [M][KP], zero-padded
__global__ void conv_split(const float* __restrict__ in, const float* __restrict__ add2,
                           ushort_t* __restrict__ H, ushort_t* __restrict__ L,
                           int M, int Kreal, int KP) {
    int i = blockIdx.x * blockDim.x + threadIdx.x;
    int total = M * KP;
    if (i >= total) return;
    int r = i / KP, k = i - r * KP;
    float v = 0.f;
    if (k < Kreal) {
        v = in[(size_t)r * Kreal + k];
        if (add2) v += add2[(size_t)r * Kreal + k];
    }
    ushort_t hh, ll;
    bf16_split(v, hh, ll);
    H[i] = hh;
    L[i] = ll;
}

// W [K][Nn] fp32 -> HT,LT ushort [NnP][KP] (transposed, zero-padded)
__global__ void conv_wT(const float* __restrict__ W, ushort_t* __restrict__ HT,
                        ushort_t* __restrict__ LT, int K, int Nn, int KP, int NnP) {
    int i = blockIdx.x * blockDim.x + threadIdx.x;
    int total = NnP * KP;
    if (i >= total) return;
    int n = i / KP, k = i - n * KP;
    float v = (n < Nn && k < K) ? W[(size_t)k * Nn + n] : 0.f;
    ushort_t hh, ll;
    bf16_split(v, hh, ll);
    HT[i] = hh;
    LT[i] = ll;
}

// ---------------- split-bf16 MFMA GEMM (R3-proven structure: 256x64, 40KB, single-stage) ----------------
#define BMg 256
#define BNg 64

__global__ __launch_bounds__(256) void gemm_split(
    const ushort_t* __restrict__ AH, const ushort_t* __restrict__ AL, int KP,
    const ushort_t* __restrict__ BH, const ushort_t* __restrict__ BL,
    const float* __restrict__ bias, const float* __restrict__ gg,
    const float* __restrict__ bb, const float* __restrict__ bm,
    const float* __restrict__ bv,
    int Mc, int NnReal, int relu,
    float* __restrict__ outF, int ldF,
    ushort_t* __restrict__ outH, ushort_t* __restrict__ outL, int ldP)
{
    __shared__ ushort_t sAH[BMg * 32];   // 16 KB, swizzled quad layout
    __shared__ ushort_t sAL[BMg * 32];
    __shared__ ushort_t sBH[BNg * 32];   // 4 KB
    __shared__ ushort_t sBL[BNg * 32];

    const int tid = threadIdx.x;
    const int lane = tid & 63;
    const int w = tid >> 6;
    const int m0 = blockIdx.y * BMg;
    const int n0 = blockIdx.x * BNg;

    // DMA slots: s = row*4 + q'; q' = (q + (row>>1)) & 3 swizzle; LDS base wave-uniform.
    const ushort_t* gA[8];
    ushort_t* lA[8];
    const ushort_t* gB[2];
    ushort_t* lB[2];
#pragma unroll
    for (int i = 0; i < 4; ++i) {
        int s = w * 256 + i * 64 + lane;
        int m = s >> 2, qp = s & 3;
        int q = (qp - (m >> 1)) & 3;
        int msrc = (m0 + m < Mc) ? (m0 + m) : (Mc - 1);
        gA[i]     = AH + (size_t)msrc * KP + 8 * q;
        gA[i + 4] = AL + (size_t)msrc * KP + 8 * q;
        lA[i]     = sAH + (w * 256 + i * 64) * 8;
        lA[i + 4] = sAL + (w * 256 + i * 64) * 8;
    }
    {
        int s = w * 64 + lane;
        int n = s >> 2, qp = s & 3;
        int q = (qp - (n >> 1)) & 3;
        gB[0] = BH + (size_t)(n0 + n) * KP + 8 * q;
        gB[1] = BL + (size_t)(n0 + n) * KP + 8 * q;
        lB[0] = sBH + (w * 64) * 8;
        lB[1] = sBL + (w * 64) * 8;
    }

    f32x4 acc[4][4];
#pragma unroll
    for (int a = 0; a < 4; ++a)
#pragma unroll
        for (int b = 0; b < 4; ++b) acc[a][b] = (f32x4)(0.f);

    const int q = lane >> 4;
    const int c16 = lane & 15;
    const int kt = KP >> 5;

    for (int t = 0; t < kt; ++t) {
        if (t) __syncthreads();
#pragma unroll
        for (int i = 0; i < 8; ++i) { dma16(gA[i], lA[i]); gA[i] += 32; }
        dma16(gB[0], lB[0]); gB[0] += 32;
        dma16(gB[1], lB[1]); gB[1] += 32;
        __syncthreads();

        short8 ah[4], al[4], bh[4], bl[4];
#pragma unroll
        for (int tt = 0; tt < 4; ++tt) {
            int m = w * 64 + tt * 16 + c16;
            int q2 = (q + (m >> 1)) & 3;
            int off = m * 32 + q2 * 8;
            ah[tt] = *(const short8*)(sAH + off);
            al[tt] = *(const short8*)(sAL + off);
        }
#pragma unroll
        for (int uu = 0; uu < 4; ++uu) {
            int n = uu * 16 + c16;
            int q2 = (q + (n >> 1)) & 3;
            int off = n * 32 + q2 * 8;
            bh[uu] = *(const short8*)(sBH + off);
            bl[uu] = *(const short8*)(sBL + off);
        }
#pragma unroll
        for (int tt = 0; tt < 4; ++tt)
#pragma unroll
            for (int uu = 0; uu < 4; ++uu) {
                acc[tt][uu] = __builtin_amdgcn_mfma_f32_16x16x32_bf16(ah[tt], bh[uu], acc[tt][uu], 0, 0, 0);
                acc[tt][uu] = __builtin_amdgcn_mfma_f32_16x16x32_bf16(ah[tt], bl[uu], acc[tt][uu], 0, 0, 0);
                acc[tt][uu] = __builtin_amdgcn_mfma_f32_16x16x32_bf16(al[tt], bh[uu], acc[tt][uu], 0, 0, 0);
            }
    }

    // epilogue: C/D layout col=lane&15, row=q*4+r
#pragma unroll
    for (int uu = 0; uu < 4; ++uu) {
        int gn = n0 + uu * 16 + c16;
        float sc = 0.f, sh = 0.f;
        if (gn < NnReal) {
            sc = gg[gn] * rsqrtf(bv[gn] + 1e-5f);
            sh = bb[gn] + (bias[gn] - bm[gn]) * sc;
        }
#pragma unroll
        for (int tt = 0; tt < 4; ++tt) {
            int rbase = m0 + w * 64 + tt * 16 + q * 4;
#pragma unroll
            for (int r = 0; r < 4; ++r) {
                int gm = rbase + r;
                if (gm >= Mc) continue;
                float y = acc[tt][uu][r] * sc + sh;
                if (relu) y = fmaxf(y, 0.f);
                if (outF) {
                    if (gn < NnReal) outF[(size_t)gm * ldF + gn] = y;
                } else {
                    ushort_t hh, ll;
                    bf16_split(y, hh, ll);
                    outH[(size_t)gm * ldP + gn] = hh;
                    outL[(size_t)gm * ldP + gn] = ll;
                }
            }
        }
    }
}

// ---------------- host-side MLP ----------------

struct MlpW {
    const float *W1, *b1, *g1, *be1, *m1, *v1;
    const float *W2, *b2, *g2, *be2, *m2, *v2;
};

// inputs already split: inH/inL [M][KP1] -> outF fp32 [M][300]
static void run_mlp(hipStream_t stream, const ushort_t* inH, const ushort_t* inL, int M,
                    ushort_t* w1h, ushort_t* w1l, ushort_t* w2h, ushort_t* w2l,
                    ushort_t* tH, ushort_t* tL, int CH,
                    const MlpW& W, float* outF, int relu2) {
    const int BLK = 256;
    conv_wT<<<cdiv(NP1 * KP1, BLK), BLK, 0, stream>>>(W.W1, w1h, w1l, EMBD, 2 * EMBD, KP1, NP1);
    conv_wT<<<cdiv(NP2 * KP2, BLK), BLK, 0, stream>>>(W.W2, w2h, w2l, 2 * EMBD, EMBD, KP2, NP2);
    for (int c0 = 0; c0 < M; c0 += CH) {
        int Mc = (M - c0 < CH) ? (M - c0) : CH;
        {
            dim3 grid(NP1 / BNg, cdiv(Mc, BMg));
            gemm_split<<<grid, 256, 0, stream>>>(
                inH + (size_t)c0 * KP1, inL + (size_t)c0 * KP1, KP1, w1h, w1l,
                W.b1, W.g1, W.be1, W.m1, W.v1,
                Mc, 2 * EMBD, 1,
                nullptr, 0, tH, tL, KP2);
        }
        {
            dim3 grid(NP2 / BNg, cdiv(Mc, BMg));
            gemm_split<<<grid, 256, 0, stream>>>(
                tH, tL, KP2, w2h, w2l,
                W.b2, W.g2, W.be2, W.m2, W.v2,
                Mc, EMBD, relu2,
                outF + (size_t)c0 * EMBD, EMBD, nullptr, nullptr, 0);
        }
    }
}

// ---------------- entry ----------------

extern "C" void kernel_launch(void* const* d_in, const int* in_sizes, int n_in,
                              void* d_out, int out_size, void* d_ws, size_t ws_size,
                              hipStream_t stream) {
    const int*   x        = (const int*)d_in[0];
    const int*   ei       = (const int*)d_in[1];
    const int*   ea       = (const int*)d_in[2];
    const int*   batch    = (const int*)d_in[3];
    const float* atom_emb = (const float*)d_in[4];
    const float* bond_emb = (const float*)d_in[5];
    const float* vn_emb   = (const float*)d_in[6];
    const float* gin_eps  = (const float*)d_in[7];
    const float* gin_W1   = (const float*)d_in[8];
    const float* gin_b1   = (const float*)d_in[9];
    const float* gin_bn1g = (const float*)d_in[10];
    const float* gin_bn1b = (const float*)d_in[11];
    const float* gin_bn1m = (const float*)d_in[12];
    const float* gin_bn1v = (const float*)d_in[13];
    const float* gin_W2   = (const float*)d_in[14];
    const float* gin_b2   = (const float*)d_in[15];
    const float* bn_g     = (const float*)d_in[16];
    const float* bn_b     = (const float*)d_in[17];
    const float* bn_m     = (const float*)d_in[18];
    const float* bn_v     = (const float*)d_in[19];
    const float* vn_W1    = (const float*)d_in[20];
    const float* vn_b1    = (const float*)d_in[21];
    const float* vn_bn1g  = (const float*)d_in[22];
    const float* vn_bn1b  = (const float*)d_in[23];
    const float* vn_bn1m  = (const float*)d_in[24];
    const float* vn_bn1v  = (const float*)d_in[25];
    const float* vn_W2    = (const float*)d_in[26];
    const float* vn_b2    = (const float*)d_in[27];
    const float* vn_bn2g  = (const float*)d_in[28];
    const float* vn_bn2b  = (const float*)d_in[29];
    const float* vn_bn2m  = (const float*)d_in[30];
    const float* vn_bn2v  = (const float*)d_in[31];

    const int N = in_sizes[3];
    const int E = in_sizes[1] / 2;

    // ---- workspace layout (bytes); fixed ~264 MB ----
    char* base = (char*)d_ws;
    size_t off = 0;
    float* hbuf   = (float*)(base + off); off += (size_t)N * EMBD * 4;
    ushort_t* aggH = (ushort_t*)(base + off); off += (size_t)N * KP1 * 2;
    ushort_t* aggL = (ushort_t*)(base + off); off += (size_t)N * KP1 * 2;
    float* vnbuf  = (float*)(base + off); off += (size_t)GG * EMBD * 4;
    float* pooled = (float*)(base + off); off += (size_t)GG * EMBD * 4;
    int*   starts = (int*)(base + off);   off += 4104 * 4;
    int*   cnt    = (int*)(base + off);   off += (size_t)N * 4;
    int*   cursor = (int*)(base + off);   off += (size_t)N * 4;
    int*   estart = (int*)(base + off);   off += ((size_t)N + 8) * 4;
    int*   ebucket= (int*)(base + off);   off += (size_t)E * 4;
    ushort_t* w1h = (ushort_t*)(base + off); off += (size_t)NP1 * KP1 * 2;
    ushort_t* w1l = (ushort_t*)(base + off); off += (size_t)NP1 * KP1 * 2;
    ushort_t* w2h = (ushort_t*)(base + off); off += (size_t)NP2 * KP2 * 2;
    ushort_t* w2l = (ushort_t*)(base + off); off += (size_t)NP2 * KP2 * 2;
    ushort_t* vnaH = (ushort_t*)(base + off); off += (size_t)GG * KP1 * 2;
    ushort_t* vnaL = (ushort_t*)(base + off); off += (size_t)GG * KP1 * 2;
    off = (off + 255) & ~(size_t)255;

    // adaptive chunk for tH/tL: 2560 B per row
    size_t avail = (ws_size > off) ? ws_size - off : 0;
    int CH = (int)(avail / 2560);
    CH &= ~255;
    if (CH > N) CH = (N + 255) & ~255;
    if (CH < 256) CH = 256;  // last resort
    ushort_t* tH = (ushort_t*)(base + off);
    ushort_t* tL = tH + (size_t)CH * KP2;

    const int BLK = 256;
    int ne4 = N * 75;

    // init + edge bucket sort (edges are layer-invariant)
    find_starts<<<cdiv(GG + 1, BLK), BLK, 0, stream>>>(batch, starts, N);
    atom_encode4<<<cdiv(ne4, BLK), BLK, 0, stream>>>(x, atom_emb, hbuf, N);
    init_vn4<<<cdiv(GG * 75, BLK), BLK, 0, stream>>>(vn_emb, vnbuf);
    hipMemsetAsync(cnt, 0, (size_t)N * 4, stream);
    ecount<<<cdiv(E, BLK), BLK, 0, stream>>>(ei, cnt, E);
    scan_counts<<<1, 1024, 0, stream>>>(cnt, estart, cursor, N, E);
    escatter<<<cdiv(E, BLK), BLK, 0, stream>>>(ei, cursor, ebucket, E);

    for (int l = 0; l < NLAY; ++l) {
        int last = (l == NLAY - 1);

        prep_vn<<<cdiv(ne4, BLK), BLK, 0, stream>>>(hbuf, vnbuf, batch, N);
        if (!last)
            pool_graphs<<<GG, 320, 0, stream>>>(hbuf, starts, pooled);

        aggregate<<<cdiv(N, NPB), NPB * 80, 0, stream>>>(
            hbuf, ei, ea, bond_emb, estart, ebucket, gin_eps + l, aggH, aggL, N, E);

        MlpW Wn = { gin_W1 + (size_t)l * EMBD * 2 * EMBD, gin_b1 + (size_t)l * 2 * EMBD,
                    gin_bn1g + (size_t)l * 2 * EMBD, gin_bn1b + (size_t)l * 2 * EMBD,
                    gin_bn1m + (size_t)l * 2 * EMBD, gin_bn1v + (size_t)l * 2 * EMBD,
                    gin_W2 + (size_t)l * 2 * EMBD * EMBD, gin_b2 + (size_t)l * EMBD,
                    bn_g + (size_t)l * EMBD, bn_b + (size_t)l * EMBD,
                    bn_m + (size_t)l * EMBD, bn_v + (size_t)l * EMBD };
        run_mlp(stream, aggH, aggL, N, w1h, w1l, w2h, w2l, tH, tL, CH,
                Wn, hbuf, last ? 0 : 1);

        if (!last) {
            conv_split<<<cdiv(GG * KP1, BLK), BLK, 0, stream>>>(
                pooled, vnbuf, vnaH, vnaL, GG, EMBD, KP1);
            MlpW Wv = { vn_W1 + (size_t)l * EMBD * 2 * EMBD, vn_b1 + (size_t)l * 2 * EMBD,
                        vn_bn1g + (size_t)l * 2 * EMBD, vn_bn1b + (size_t)l * 2 * EMBD,
                        vn_bn1m + (size_t)l * 2 * EMBD, vn_bn1v + (size_t)l * 2 * EMBD,
                        vn_W2 + (size_t)l * 2 * EMBD * EMBD, vn_b2 + (size_t)l * EMBD,
                        vn_bn2g + (size_t)l * EMBD, vn_bn2b + (size_t)l * EMBD,
                        vn_bn2m + (size_t)l * EMBD, vn_bn2v + (size_t)l * EMBD };
            run_mlp(stream, vnaH, vnaL, GG, w1h, w1l, w2h, w2l, tH, tL, CH,
                    Wv, vnbuf, 1);
        }
    }

    pool_mean<<<GG, 320, 0, stream>>>(hbuf, starts, (float*)d_out);
}

// Round 6
// 3093.922 us; speedup vs baseline: 15.9774x; 15.9774x over previous
//
#include <hip/hip_runtime.h>
#include <hip/hip_bf16.h>

#define EMBD 300
#define GG   4096
#define NLAY 5
#define KP1  320   // padded K for EMB=300 inputs
#define KP2  640   // padded K for 2*EMB=600 inputs
#define NP1  640   // padded B-rows / out-cols for 600
#define NP2  320   // padded B-rows for 300-col GEMM2

typedef unsigned short ushort_t;
typedef short short8 __attribute__((ext_vector_type(8)));
typedef short short4v __attribute__((ext_vector_type(4)));
typedef float f32x4 __attribute__((ext_vector_type(4)));

static inline int cdiv(int a, int b) { return (a + b - 1) / b; }

// ---------------- helpers ----------------

__device__ inline void dma16(const ushort_t* g, ushort_t* l) {
    __builtin_amdgcn_global_load_lds(
        (const __attribute__((address_space(1))) unsigned int*)g,
        (__attribute__((address_space(3))) unsigned int*)l, 16, 0, 0);
}

__device__ inline void bf16_split(float v, ushort_t& h, ushort_t& l) {
    union { __hip_bfloat16 b; ushort_t u; } c;
    c.b = __float2bfloat16(v);
    h = c.u;
    float hf = __bfloat162float(c.b);
    c.b = __float2bfloat16(v - hf);
    l = c.u;
}

__device__ inline ushort_t bf16_of(float v) {
    union { __hip_bfloat16 b; ushort_t u; } c;
    c.b = __float2bfloat16(v);
    return c.u;
}

// ---------------- elementwise kernels ----------------

__global__ void atom_encode4(const int* __restrict__ x, const float* __restrict__ aemb,
                             float* __restrict__ h, int N) {
    int i = blockIdx.x * blockDim.x + threadIdx.x;
    int total = N * 75;
    if (i >= total) return;
    int n = i / 75, d4 = i - n * 75;
    const int* xr = x + n * 9;
    float4 s = make_float4(0.f, 0.f, 0.f, 0.f);
    const float4* a4 = (const float4*)aemb;
#pragma unroll
    for (int f = 0; f < 9; ++f) {
        float4 v = a4[(size_t)((f << 7) + xr[f]) * 75 + d4];
        s.x += v.x; s.y += v.y; s.z += v.z; s.w += v.w;
    }
    ((float4*)h)[i] = s;
}

__global__ void init_vn4(const float* __restrict__ vn_emb, float* __restrict__ vn) {
    int i = blockIdx.x * blockDim.x + threadIdx.x;
    if (i >= GG * 75) return;
    ((float4*)vn)[i] = ((const float4*)vn_emb)[i % 75];
}

__global__ void find_starts(const int* __restrict__ batch, int* __restrict__ starts, int N) {
    int g = blockIdx.x * blockDim.x + threadIdx.x;
    if (g > GG) return;
    int lo = 0, hi = N;
    while (lo < hi) {
        int mid = (lo + hi) >> 1;
        if (batch[mid] < g) lo = mid + 1; else hi = mid;
    }
    starts[g] = lo;
}

// h += vn[batch]  (in place)
__global__ void prep_vn(float* __restrict__ h, const float* __restrict__ vn,
                        const int* __restrict__ batch, int N) {
    int i = blockIdx.x * blockDim.x + threadIdx.x;
    int total = N * 75;
    if (i >= total) return;
    int n = i / 75, d4 = i - n * 75;
    float4 hv = ((const float4*)h)[i];
    float4 vv = ((const float4*)vn)[(size_t)batch[n] * 75 + d4];
    hv.x += vv.x; hv.y += vv.y; hv.z += vv.z; hv.w += vv.w;
    ((float4*)h)[i] = hv;
}

__global__ void pool_graphs(const float* __restrict__ h, const int* __restrict__ starts,
                            float* __restrict__ pooled) {
    int g = blockIdx.x;
    int t = threadIdx.x;
    if (t >= EMBD) return;
    int s0 = starts[g], s1 = starts[g + 1];
    float s = 0.f;
    for (int n = s0; n < s1; ++n) s += h[(size_t)n * EMBD + t];
    pooled[(size_t)g * EMBD + t] = s;
}

__global__ void pool_mean(const float* __restrict__ h, const int* __restrict__ starts,
                          float* __restrict__ out) {
    int g = blockIdx.x;
    int t = threadIdx.x;
    if (t >= EMBD) return;
    int s0 = starts[g], s1 = starts[g + 1];
    float s = 0.f;
    for (int n = s0; n < s1; ++n) s += h[(size_t)n * EMBD + t];
    float cnt = (float)(s1 - s0);
    out[(size_t)g * EMBD + t] = s / fmaxf(cnt, 1.0f);
}

// ---------------- edge bucket sort (once per launch) ----------------

__global__ void ecount(const int* __restrict__ ei, int* __restrict__ cnt, int E) {
    int e = blockIdx.x * blockDim.x + threadIdx.x;
    if (e >= E) return;
    atomicAdd(&cnt[ei[E + e]], 1);
}

__global__ void scan_counts(const int* __restrict__ cnt, int* __restrict__ estart,
                            int* __restrict__ cursor, int N, int E) {
    __shared__ int part[1024];
    int tid = threadIdx.x;
    int vpt = (N + 1023) >> 10;
    int lo = tid * vpt, hi = lo + vpt;
    if (hi > N) hi = N;
    int s = 0;
    for (int j = lo; j < hi; ++j) s += cnt[j];
    part[tid] = s;
    __syncthreads();
    for (int d = 1; d < 1024; d <<= 1) {
        int v = (tid >= d) ? part[tid - d] : 0;
        __syncthreads();
        part[tid] += v;
        __syncthreads();
    }
    int run = part[tid] - s;
    for (int j = lo; j < hi; ++j) { estart[j] = run; cursor[j] = run; run += cnt[j]; }
    if (tid == 0) estart[N] = E;
}

__global__ void escatter(const int* __restrict__ ei, int* __restrict__ cursor,
                         int* __restrict__ ebucket, int E) {
    int e = blockIdx.x * blockDim.x + threadIdx.x;
    if (e >= E) return;
    int c = ei[E + e];
    int p = atomicAdd(&cursor[c], 1);
    ebucket[p] = e;
}

// ---------------- fused aggregate: (1+eps)h + sum relu(h[row]+bond) -> single bf16 ----------------
#define NPB 4   // nodes per block; blockDim = NPB*80 = 320

__global__ void aggregate(const float* __restrict__ h, const int* __restrict__ ei,
                          const int* __restrict__ ea, const float* __restrict__ bemb,
                          const int* __restrict__ estart, const int* __restrict__ ebucket,
                          const float* __restrict__ epsp,
                          ushort_t* __restrict__ aggB, int N, int E) {
    int n = blockIdx.x * NPB + threadIdx.x / 80;
    int slot = threadIdx.x % 80;
    if (n >= N) return;
    float4 acc = make_float4(0.f, 0.f, 0.f, 0.f);
    if (slot < 75) {
        const float4* h4 = (const float4*)h;
        const float4* b4 = (const float4*)bemb;
        float ce = 1.0f + *epsp;
        float4 hv = h4[(size_t)n * 75 + slot];
        acc = make_float4(ce * hv.x, ce * hv.y, ce * hv.z, ce * hv.w);
        int p0 = estart[n], p1 = estart[n + 1];
        for (int p = p0; p < p1; ++p) {
            int e = ebucket[p];
            int r = ei[e];
            int a0 = ea[3 * e], a1 = ea[3 * e + 1], a2 = ea[3 * e + 2];
            float4 xv = h4[(size_t)r * 75 + slot];
            float4 e0 = b4[(size_t)a0 * 75 + slot];
            float4 e1 = b4[(size_t)(8 + a1) * 75 + slot];
            float4 e2 = b4[(size_t)(16 + a2) * 75 + slot];
            acc.x += fmaxf(xv.x + e0.x + e1.x + e2.x, 0.f);
            acc.y += fmaxf(xv.y + e0.y + e1.y + e2.y, 0.f);
            acc.z += fmaxf(xv.z + e0.z + e1.z + e2.z, 0.f);
            acc.w += fmaxf(xv.w + e0.w + e1.w + e2.w, 0.f);
        }
    }
    short4v bv4;
    bv4[0] = (short)bf16_of(acc.x);
    bv4[1] = (short)bf16_of(acc.y);
    bv4[2] = (short)bf16_of(acc.z);
    bv4[3] = (short)bf16_of(acc.w);
    *(short4v*)(aggB + (size_t)n * KP1 + slot * 4) = bv4;
}

// ---------------- conversion kernels ----------------

// in [M][300] fp32 + add2 -> single bf16 [M][KP1], zero-padded
__global__ void conv_single(const float* __restrict__ in, const float* __restrict__ add2,
                            ushort_t* __restrict__ B, int M) {
    int i = blockIdx.x * blockDim.x + threadIdx.x;
    int total = M * KP1;
    if (i >= total) return;
    int r = i / KP1, k = i - r * KP1;
    float v = 0.f;
    if (k < EMBD) {
        v = in[(size_t)r * EMBD + k];
        if (add2) v += add2[(size_t)r * EMBD + k];
    }
    B[i] = bf16_of(v);
}

// W [K][Nn] fp32 -> HT,LT ushort [NnP][KP] (transposed split pair, zero-padded)
__global__ void conv_wT(const float* __restrict__ W, ushort_t* __restrict__ HT,
                        ushort_t* __restrict__ LT, int K, int Nn, int KP, int NnP) {
    int i = blockIdx.x * blockDim.x + threadIdx.x;
    int total = NnP * KP;
    if (i >= total) return;
    int n = i / KP, k = i - n * KP;
    float v = (n < Nn && k < K) ? W[(size_t)k * Nn + n] : 0.f;
    ushort_t hh, ll;
    bf16_split(v, hh, ll);
    HT[i] = hh;
    LT[i] = ll;
}

// ---------------- MFMA GEMM: A single bf16, B split pair, 256x64 tile ----------------
#define BMg 256
#define BNg 64

__global__ __launch_bounds__(256) void gemm_as(
    const ushort_t* __restrict__ A, int KP,
    const ushort_t* __restrict__ BH, const ushort_t* __restrict__ BL,
    const float* __restrict__ bias, const float* __restrict__ gg,
    const float* __restrict__ bb, const float* __restrict__ bm,
    const float* __restrict__ bv,
    int Mc, int NnReal, int relu,
    float* __restrict__ outF, int ldF,
    ushort_t* __restrict__ outB, int ldP)
{
    __shared__ ushort_t sA[BMg * 32];    // 16 KB, swizzled quad layout
    __shared__ ushort_t sBH[BNg * 32];   // 4 KB
    __shared__ ushort_t sBL[BNg * 32];   // 4 KB  (total 24 KB)

    const int tid = threadIdx.x;
    const int lane = tid & 63;
    const int w = tid >> 6;
    const int m0 = blockIdx.y * BMg;
    const int n0 = blockIdx.x * BNg;

    // DMA slots: s = row*4 + q'; q' = (q + (row>>1)) & 3 swizzle; LDS base wave-uniform.
    const ushort_t* gA[4];
    ushort_t* lA[4];
    const ushort_t* gB[2];
    ushort_t* lB[2];
#pragma unroll
    for (int i = 0; i < 4; ++i) {
        int s = w * 256 + i * 64 + lane;
        int m = s >> 2, qp = s & 3;
        int q = (qp - (m >> 1)) & 3;
        int msrc = (m0 + m < Mc) ? (m0 + m) : (Mc - 1);
        gA[i] = A + (size_t)msrc * KP + 8 * q;
        lA[i] = sA + (w * 256 + i * 64) * 8;
    }
    {
        int s = w * 64 + lane;
        int n = s >> 2, qp = s & 3;
        int q = (qp - (n >> 1)) & 3;
        gB[0] = BH + (size_t)(n0 + n) * KP + 8 * q;
        gB[1] = BL + (size_t)(n0 + n) * KP + 8 * q;
        lB[0] = sBH + (w * 64) * 8;
        lB[1] = sBL + (w * 64) * 8;
    }

    f32x4 acc[4][4];
#pragma unroll
    for (int a = 0; a < 4; ++a)
#pragma unroll
        for (int b = 0; b < 4; ++b) acc[a][b] = (f32x4)(0.f);

    const int q = lane >> 4;
    const int c16 = lane & 15;
    const int kt = KP >> 5;

    for (int t = 0; t < kt; ++t) {
        if (t) __syncthreads();
#pragma unroll
        for (int i = 0; i < 4; ++i) { dma16(gA[i], lA[i]); gA[i] += 32; }
        dma16(gB[0], lB[0]); gB[0] += 32;
        dma16(gB[1], lB[1]); gB[1] += 32;
        __syncthreads();

        short8 av[4], bh[4], bl[4];
#pragma unroll
        for (int tt = 0; tt < 4; ++tt) {
            int m = w * 64 + tt * 16 + c16;
            int q2 = (q + (m >> 1)) & 3;
            av[tt] = *(const short8*)(sA + m * 32 + q2 * 8);
        }
#pragma unroll
        for (int uu = 0; uu < 4; ++uu) {
            int n = uu * 16 + c16;
            int q2 = (q + (n >> 1)) & 3;
            int off = n * 32 + q2 * 8;
            bh[uu] = *(const short8*)(sBH + off);
            bl[uu] = *(const short8*)(sBL + off);
        }
#pragma unroll
        for (int tt = 0; tt < 4; ++tt)
#pragma unroll
            for (int uu = 0; uu < 4; ++uu) {
                acc[tt][uu] = __builtin_amdgcn_mfma_f32_16x16x32_bf16(av[tt], bh[uu], acc[tt][uu], 0, 0, 0);
                acc[tt][uu] = __builtin_amdgcn_mfma_f32_16x16x32_bf16(av[tt], bl[uu], acc[tt][uu], 0, 0, 0);
            }
    }

    // epilogue: C/D layout col=lane&15, row=q*4+r
#pragma unroll
    for (int uu = 0; uu < 4; ++uu) {
        int gn = n0 + uu * 16 + c16;
        float sc = 0.f, sh = 0.f;
        if (gn < NnReal) {
            sc = gg[gn] * rsqrtf(bv[gn] + 1e-5f);
            sh = bb[gn] + (bias[gn] - bm[gn]) * sc;
        }
#pragma unroll
        for (int tt = 0; tt < 4; ++tt) {
            int rbase = m0 + w * 64 + tt * 16 + q * 4;
#pragma unroll
            for (int r = 0; r < 4; ++r) {
                int gm = rbase + r;
                if (gm >= Mc) continue;
                float y = acc[tt][uu][r] * sc + sh;
                if (relu) y = fmaxf(y, 0.f);
                if (outF) {
                    if (gn < NnReal) outF[(size_t)gm * ldF + gn] = y;
                } else {
                    if (gn < ldP) outB[(size_t)gm * ldP + gn] = bf16_of(y);
                }
            }
        }
    }
}

// ---------------- host-side MLP ----------------

struct MlpW {
    const float *W1, *b1, *g1, *be1, *m1, *v1;
    const float *W2, *b2, *g2, *be2, *m2, *v2;
};

// input already bf16 [M][KP1] -> outF fp32 [M][300]
static void run_mlp(hipStream_t stream, const ushort_t* inB, int M,
                    ushort_t* w1h, ushort_t* w1l, ushort_t* w2h, ushort_t* w2l,
                    ushort_t* tB, int CH,
                    const MlpW& W, float* outF, int relu2) {
    const int BLK = 256;
    conv_wT<<<cdiv(NP1 * KP1, BLK), BLK, 0, stream>>>(W.W1, w1h, w1l, EMBD, 2 * EMBD, KP1, NP1);
    conv_wT<<<cdiv(NP2 * KP2, BLK), BLK, 0, stream>>>(W.W2, w2h, w2l, 2 * EMBD, EMBD, KP2, NP2);
    for (int c0 = 0; c0 < M; c0 += CH) {
        int Mc = (M - c0 < CH) ? (M - c0) : CH;
        {
            dim3 grid(NP1 / BNg, cdiv(Mc, BMg));
            gemm_as<<<grid, 256, 0, stream>>>(
                inB + (size_t)c0 * KP1, KP1, w1h, w1l,
                W.b1, W.g1, W.be1, W.m1, W.v1,
                Mc, 2 * EMBD, 1,
                nullptr, 0, tB, KP2);
        }
        {
            dim3 grid(NP2 / BNg, cdiv(Mc, BMg));
            gemm_as<<<grid, 256, 0, stream>>>(
                tB, KP2, w2h, w2l,
                W.b2, W.g2, W.be2, W.m2, W.v2,
                Mc, EMBD, relu2,
                outF + (size_t)c0 * EMBD, EMBD, nullptr, 0);
        }
    }
}

// ---------------- entry ----------------

extern "C" void kernel_launch(void* const* d_in, const int* in_sizes, int n_in,
                              void* d_out, int out_size, void* d_ws, size_t ws_size,
                              hipStream_t stream) {
    const int*   x        = (const int*)d_in[0];
    const int*   ei       = (const int*)d_in[1];
    const int*   ea       = (const int*)d_in[2];
    const int*   batch    = (const int*)d_in[3];
    const float* atom_emb = (const float*)d_in[4];
    const float* bond_emb = (const float*)d_in[5];
    const float* vn_emb   = (const float*)d_in[6];
    const float* gin_eps  = (const float*)d_in[7];
    const float* gin_W1   = (const float*)d_in[8];
    const float* gin_b1   = (const float*)d_in[9];
    const float* gin_bn1g = (const float*)d_in[10];
    const float* gin_bn1b = (const float*)d_in[11];
    const float* gin_bn1m = (const float*)d_in[12];
    const float* gin_bn1v = (const float*)d_in[13];
    const float* gin_W2   = (const float*)d_in[14];
    const float* gin_b2   = (const float*)d_in[15];
    const float* bn_g     = (const float*)d_in[16];
    const float* bn_b     = (const float*)d_in[17];
    const float* bn_m     = (const float*)d_in[18];
    const float* bn_v     = (const float*)d_in[19];
    const float* vn_W1    = (const float*)d_in[20];
    const float* vn_b1    = (const float*)d_in[21];
    const float* vn_bn1g  = (const float*)d_in[22];
    const float* vn_bn1b  = (const float*)d_in[23];
    const float* vn_bn1m  = (const float*)d_in[24];
    const float* vn_bn1v  = (const float*)d_in[25];
    const float* vn_W2    = (const float*)d_in[26];
    const float* vn_b2    = (const float*)d_in[27];
    const float* vn_bn2g  = (const float*)d_in[28];
    const float* vn_bn2b  = (const float*)d_in[29];
    const float* vn_bn2m  = (const float*)d_in[30];
    const float* vn_bn2v  = (const float*)d_in[31];

    const int N = in_sizes[3];
    const int E = in_sizes[1] / 2;

    // ---- workspace layout (bytes); fixed ~198 MB (ws_size appears to be ~256 MiB:
    // R1 crashed at 623 MB, R4/R5's 267 MB fixed collapsed CH to ~512 -> launch-bound) ----
    char* base = (char*)d_ws;
    size_t off = 0;
    float* hbuf    = (float*)(base + off);    off += (size_t)N * EMBD * 4;   // 120 MB
    ushort_t* aggB = (ushort_t*)(base + off); off += (size_t)N * KP1 * 2;    // 64 MB
    float* vnbuf   = (float*)(base + off);    off += (size_t)GG * EMBD * 4;
    float* pooled  = (float*)(base + off);    off += (size_t)GG * EMBD * 4;
    int*   starts  = (int*)(base + off);      off += 4104 * 4;
    int*   cnt     = (int*)(base + off);      off += (size_t)N * 4;
    int*   cursor  = (int*)(base + off);      off += (size_t)N * 4;
    int*   estart  = (int*)(base + off);      off += ((size_t)N + 8) * 4;
    int*   ebucket = (int*)(base + off);      off += (size_t)E * 4;
    ushort_t* w1h  = (ushort_t*)(base + off); off += (size_t)NP1 * KP1 * 2;
    ushort_t* w1l  = (ushort_t*)(base + off); off += (size_t)NP1 * KP1 * 2;
    ushort_t* w2h  = (ushort_t*)(base + off); off += (size_t)NP2 * KP2 * 2;
    ushort_t* w2l  = (ushort_t*)(base + off); off += (size_t)NP2 * KP2 * 2;
    ushort_t* vnaB = (ushort_t*)(base + off); off += (size_t)GG * KP1 * 2;
    off = (off + 255) & ~(size_t)255;

    // adaptive chunk for tB: KP2*2 = 1280 B per row
    size_t avail = (ws_size > off) ? ws_size - off : 0;
    int CH = (int)(avail / (KP2 * 2));
    CH &= ~255;
    if (CH > N) CH = (N + 255) & ~255;
    if (CH < 2048) CH = 2048;  // last resort (still correct, just slower)
    ushort_t* tB = (ushort_t*)(base + off);

    const int BLK = 256;
    int ne4 = N * 75;

    // init + edge bucket sort (edges are layer-invariant)
    find_starts<<<cdiv(GG + 1, BLK), BLK, 0, stream>>>(batch, starts, N);
    atom_encode4<<<cdiv(ne4, BLK), BLK, 0, stream>>>(x, atom_emb, hbuf, N);
    init_vn4<<<cdiv(GG * 75, BLK), BLK, 0, stream>>>(vn_emb, vnbuf);
    hipMemsetAsync(cnt, 0, (size_t)N * 4, stream);
    ecount<<<cdiv(E, BLK), BLK, 0, stream>>>(ei, cnt, E);
    scan_counts<<<1, 1024, 0, stream>>>(cnt, estart, cursor, N, E);
    escatter<<<cdiv(E, BLK), BLK, 0, stream>>>(ei, cursor, ebucket, E);

    for (int l = 0; l < NLAY; ++l) {
        int last = (l == NLAY - 1);

        prep_vn<<<cdiv(ne4, BLK), BLK, 0, stream>>>(hbuf, vnbuf, batch, N);
        if (!last)
            pool_graphs<<<GG, 320, 0, stream>>>(hbuf, starts, pooled);

        // full-N aggregation BEFORE any in-place h update (race-free)
        aggregate<<<cdiv(N, NPB), NPB * 80, 0, stream>>>(
            hbuf, ei, ea, bond_emb, estart, ebucket, gin_eps + l, aggB, N, E);

        MlpW Wn = { gin_W1 + (size_t)l * EMBD * 2 * EMBD, gin_b1 + (size_t)l * 2 * EMBD,
                    gin_bn1g + (size_t)l * 2 * EMBD, gin_bn1b + (size_t)l * 2 * EMBD,
                    gin_bn1m + (size_t)l * 2 * EMBD, gin_bn1v + (size_t)l * 2 * EMBD,
                    gin_W2 + (size_t)l * 2 * EMBD * EMBD, gin_b2 + (size_t)l * EMBD,
                    bn_g + (size_t)l * EMBD, bn_b + (size_t)l * EMBD,
                    bn_m + (size_t)l * EMBD, bn_v + (size_t)l * EMBD };
        run_mlp(stream, aggB, N, w1h, w1l, w2h, w2l, tB, CH, Wn, hbuf, last ? 0 : 1);

        if (!last) {
            conv_single<<<cdiv(GG * KP1, BLK), BLK, 0, stream>>>(pooled, vnbuf, vnaB, GG);
            MlpW Wv = { vn_W1 + (size_t)l * EMBD * 2 * EMBD, vn_b1 + (size_t)l * 2 * EMBD,
                        vn_bn1g + (size_t)l * 2 * EMBD, vn_bn1b + (size_t)l * 2 * EMBD,
                        vn_bn1m + (size_t)l * 2 * EMBD, vn_bn1v + (size_t)l * 2 * EMBD,
                        vn_W2 + (size_t)l * 2 * EMBD * EMBD, vn_b2 + (size_t)l * EMBD,
                        vn_bn2g + (size_t)l * EMBD, vn_bn2b + (size_t)l * EMBD,
                        vn_bn2m + (size_t)l * EMBD, vn_bn2v + (size_t)l * EMBD };
            run_mlp(stream, vnaB, GG, w1h, w1l, w2h, w2l, tB, CH, Wv, vnbuf, 1);
        }
    }

    pool_mean<<<GG, 320, 0, stream>>>(hbuf, starts, (float*)d_out);
}

// Round 7
// 2765.661 us; speedup vs baseline: 17.8738x; 1.1187x over previous
//
#include <hip/hip_runtime.h>
#include <hip/hip_bf16.h>

#define EMBD 300
#define GG   4096
#define NLAY 5
#define KP1  320   // padded K for EMB=300 inputs
#define KP2  640   // padded K for 2*EMB=600 inputs
#define NP1  640   // padded B-rows / out-cols for 600
#define NP2  320   // padded B-rows for 300-col GEMM2
#define WPER (NP1*KP1 + NP2*KP2)   // 409600 elems per MLP weight set

typedef unsigned short ushort_t;
typedef short short8 __attribute__((ext_vector_type(8)));
typedef short short4v __attribute__((ext_vector_type(4)));
typedef float f32x4 __attribute__((ext_vector_type(4)));

static inline int cdiv(int a, int b) { return (a + b - 1) / b; }

// ---------------- helpers ----------------

__device__ inline void dma16(const ushort_t* g, ushort_t* l) {
    __builtin_amdgcn_global_load_lds(
        (const __attribute__((address_space(1))) unsigned int*)g,
        (__attribute__((address_space(3))) unsigned int*)l, 16, 0, 0);
}

__device__ inline void bf16_split(float v, ushort_t& h, ushort_t& l) {
    union { __hip_bfloat16 b; ushort_t u; } c;
    c.b = __float2bfloat16(v);
    h = c.u;
    float hf = __bfloat162float(c.b);
    c.b = __float2bfloat16(v - hf);
    l = c.u;
}

__device__ inline ushort_t bf16_of(float v) {
    union { __hip_bfloat16 b; ushort_t u; } c;
    c.b = __float2bfloat16(v);
    return c.u;
}

// ---------------- init kernels ----------------

__global__ void atom_encode4(const int* __restrict__ x, const float* __restrict__ aemb,
                             float* __restrict__ h, int N) {
    int i = blockIdx.x * blockDim.x + threadIdx.x;
    int total = N * 75;
    if (i >= total) return;
    int n = i / 75, d4 = i - n * 75;
    const int* xr = x + n * 9;
    float4 s = make_float4(0.f, 0.f, 0.f, 0.f);
    const float4* a4 = (const float4*)aemb;
#pragma unroll
    for (int f = 0; f < 9; ++f) {
        float4 v = a4[(size_t)((f << 7) + xr[f]) * 75 + d4];
        s.x += v.x; s.y += v.y; s.z += v.z; s.w += v.w;
    }
    ((float4*)h)[i] = s;
}

__global__ void init_vn4(const float* __restrict__ vn_emb, float* __restrict__ vn) {
    int i = blockIdx.x * blockDim.x + threadIdx.x;
    if (i >= GG * 75) return;
    ((float4*)vn)[i] = ((const float4*)vn_emb)[i % 75];
}

__global__ void find_starts(const int* __restrict__ batch, int* __restrict__ starts, int N) {
    int g = blockIdx.x * blockDim.x + threadIdx.x;
    if (g > GG) return;
    int lo = 0, hi = N;
    while (lo < hi) {
        int mid = (lo + hi) >> 1;
        if (batch[mid] < g) lo = mid + 1; else hi = mid;
    }
    starts[g] = lo;
}

// bond combo table: ebsum[c][d] = bemb[a0][d]+bemb[8+a1][d]+bemb[16+a2][d], c=(a0<<6)|(a1<<3)|a2
__global__ void bond_combo(const float* __restrict__ bemb, float* __restrict__ ebsum) {
    int i = blockIdx.x * blockDim.x + threadIdx.x;
    if (i >= 512 * EMBD) return;
    int c = i / EMBD, d = i - c * EMBD;
    int a0 = c >> 6, a1 = (c >> 3) & 7, a2 = c & 7;
    ebsum[i] = bemb[a0 * EMBD + d] + bemb[(8 + a1) * EMBD + d] + bemb[(16 + a2) * EMBD + d];
}

// convert all 9 MLP weight sets (5 node + 4 vn) into transposed split-bf16 planes
__global__ void conv_all(const float* __restrict__ gW1, const float* __restrict__ gW2,
                         const float* __restrict__ vW1, const float* __restrict__ vW2,
                         ushort_t* __restrict__ wh, ushort_t* __restrict__ wl) {
    int i = blockIdx.x * blockDim.x + threadIdx.x;
    int total = WPER * 9;
    if (i >= total) return;
    int mlp = i / WPER, r = i - mlp * WPER;
    const float *W1, *W2;
    if (mlp < NLAY) {
        W1 = gW1 + (size_t)mlp * EMBD * 2 * EMBD;
        W2 = gW2 + (size_t)mlp * 2 * EMBD * EMBD;
    } else {
        int l = mlp - NLAY;
        W1 = vW1 + (size_t)l * EMBD * 2 * EMBD;
        W2 = vW2 + (size_t)l * 2 * EMBD * EMBD;
    }
    float v;
    if (r < NP1 * KP1) {
        int n = r / KP1, k = r - n * KP1;
        v = (n < 2 * EMBD && k < EMBD) ? W1[(size_t)k * (2 * EMBD) + n] : 0.f;
    } else {
        int r2 = r - NP1 * KP1;
        int n = r2 / KP2, k = r2 - n * KP2;
        v = (n < EMBD && k < 2 * EMBD) ? W2[(size_t)k * EMBD + n] : 0.f;
    }
    ushort_t hh, ll;
    bf16_split(v, hh, ll);
    wh[i] = hh;
    wl[i] = ll;
}

// ---------------- edge bucket sort (multi-block scan) ----------------

__global__ void ecount(const int* __restrict__ ei, int* __restrict__ cnt, int E) {
    int e = blockIdx.x * blockDim.x + threadIdx.x;
    if (e >= E) return;
    atomicAdd(&cnt[ei[E + e]], 1);
}

// block b sums cnt[b*1024 .. b*1024+1023] -> bsum[b]
__global__ void scan_part(const int* __restrict__ cnt, int* __restrict__ bsum, int N) {
    __shared__ int sh[256];
    int b = blockIdx.x, t = threadIdx.x;
    int base = b * 1024;
    int s = 0;
    for (int j = t; j < 1024; j += 256) {
        int idx = base + j;
        if (idx < N) s += cnt[idx];
    }
    sh[t] = s;
    __syncthreads();
    for (int d = 128; d > 0; d >>= 1) {
        if (t < d) sh[t] += sh[t + d];
        __syncthreads();
    }
    if (t == 0) bsum[b] = sh[0];
}

// single block: exclusive scan of bsum[0..nb) in place (nb <= 1024)
__global__ void scan_top(int* __restrict__ bsum, int nb) {
    __shared__ int sh[1024];
    int t = threadIdx.x;
    int v = (t < nb) ? bsum[t] : 0;
    sh[t] = v;
    __syncthreads();
    for (int d = 1; d < 1024; d <<= 1) {
        int u = (t >= d) ? sh[t - d] : 0;
        __syncthreads();
        sh[t] += u;
        __syncthreads();
    }
    if (t < nb) bsum[t] = sh[t] - v;  // exclusive
}

// block b: re-scan its 1024-chunk with base bsum[b]; write estart & cursor
__global__ void scan_final(const int* __restrict__ cnt, const int* __restrict__ bsum,
                           int* __restrict__ estart, int* __restrict__ cursor, int N, int E) {
    __shared__ int sh[256];
    int b = blockIdx.x, t = threadIdx.x;
    int base = b * 1024 + t * 4;
    int c[4];
    int s = 0;
#pragma unroll
    for (int j = 0; j < 4; ++j) {
        int idx = base + j;
        c[j] = (idx < N) ? cnt[idx] : 0;
        s += c[j];
    }
    sh[t] = s;
    __syncthreads();
    for (int d = 1; d < 256; d <<= 1) {
        int u = (t >= d) ? sh[t - d] : 0;
        __syncthreads();
        sh[t] += u;
        __syncthreads();
    }
    int run = sh[t] - s + bsum[b];
#pragma unroll
    for (int j = 0; j < 4; ++j) {
        int idx = base + j;
        if (idx < N) { estart[idx] = run; cursor[idx] = run; run += c[j]; }
    }
    if (b == 0 && t == 0) estart[N] = E;
}

// scatter edges to dest buckets as packed (src_row, bond_combo)
__global__ void escatter(const int* __restrict__ ei, const int* __restrict__ ea,
                         int* __restrict__ cursor, int2* __restrict__ epack, int E) {
    int e = blockIdx.x * blockDim.x + threadIdx.x;
    if (e >= E) return;
    int c = ei[E + e];
    int p = atomicAdd(&cursor[c], 1);
    epack[p] = make_int2(ei[e], (ea[3 * e] << 6) | (ea[3 * e + 1] << 3) | ea[3 * e + 2]);
}

// ---------------- fused per-layer elementwise ----------------

// non-last layers: h[n] += vn[g] in place; vnaB[g] = bf16(segment_sum(h_new) + vn[g])
__global__ void pool_prep(float* __restrict__ h, const float* __restrict__ vn,
                          const int* __restrict__ starts, ushort_t* __restrict__ vnaB) {
    int g = blockIdx.x;
    int t = threadIdx.x;   // 320
    if (t >= EMBD) return;
    float vng = vn[(size_t)g * EMBD + t];
    int s0 = starts[g], s1 = starts[g + 1];
    float s = 0.f;
    for (int n = s0; n < s1; ++n) {
        float v = h[(size_t)n * EMBD + t] + vng;
        h[(size_t)n * EMBD + t] = v;
        s += v;
    }
    vnaB[(size_t)g * KP1 + t] = bf16_of(s + vng);
}

// last layer: h += vn[batch] only
__global__ void prep_vn(float* __restrict__ h, const float* __restrict__ vn,
                        const int* __restrict__ batch, int N) {
    int i = blockIdx.x * blockDim.x + threadIdx.x;
    int total = N * 75;
    if (i >= total) return;
    int n = i / 75, d4 = i - n * 75;
    float4 hv = ((const float4*)h)[i];
    float4 vv = ((const float4*)vn)[(size_t)batch[n] * 75 + d4];
    hv.x += vv.x; hv.y += vv.y; hv.z += vv.z; hv.w += vv.w;
    ((float4*)h)[i] = hv;
}

__global__ void pool_mean(const float* __restrict__ h, const int* __restrict__ starts,
                          float* __restrict__ out) {
    int g = blockIdx.x;
    int t = threadIdx.x;
    if (t >= EMBD) return;
    int s0 = starts[g], s1 = starts[g + 1];
    float s = 0.f;
    for (int n = s0; n < s1; ++n) s += h[(size_t)n * EMBD + t];
    float cnt = (float)(s1 - s0);
    out[(size_t)g * EMBD + t] = s / fmaxf(cnt, 1.0f);
}

// ---------------- fused aggregate: (1+eps)h + sum relu(h[src]+bondsum) -> bf16 ----------------
#define NPB 4   // nodes per block; blockDim = NPB*80 = 320

__global__ void aggregate(const float* __restrict__ h, const float* __restrict__ ebsum,
                          const int* __restrict__ estart, const int2* __restrict__ epack,
                          const float* __restrict__ epsp,
                          ushort_t* __restrict__ aggB, int N) {
    int n = blockIdx.x * NPB + threadIdx.x / 80;
    int slot = threadIdx.x % 80;
    if (n >= N) return;
    float4 acc = make_float4(0.f, 0.f, 0.f, 0.f);
    if (slot < 75) {
        const float4* h4 = (const float4*)h;
        const float4* b4 = (const float4*)ebsum;
        float ce = 1.0f + *epsp;
        float4 hv = h4[(size_t)n * 75 + slot];
        acc = make_float4(ce * hv.x, ce * hv.y, ce * hv.z, ce * hv.w);
        int p0 = estart[n], p1 = estart[n + 1];
        for (int p = p0; p < p1; ++p) {
            int2 ep = epack[p];
            float4 xv = h4[(size_t)ep.x * 75 + slot];
            float4 ev = b4[(size_t)ep.y * 75 + slot];
            acc.x += fmaxf(xv.x + ev.x, 0.f);
            acc.y += fmaxf(xv.y + ev.y, 0.f);
            acc.z += fmaxf(xv.z + ev.z, 0.f);
            acc.w += fmaxf(xv.w + ev.w, 0.f);
        }
    }
    short4v bv4;
    bv4[0] = (short)bf16_of(acc.x);
    bv4[1] = (short)bf16_of(acc.y);
    bv4[2] = (short)bf16_of(acc.z);
    bv4[3] = (short)bf16_of(acc.w);
    *(short4v*)(aggB + (size_t)n * KP1 + slot * 4) = bv4;
}

// ---------------- MFMA GEMM: A single bf16, B split pair, 256x64 tile ----------------
#define BMg 256
#define BNg 64

__global__ __launch_bounds__(256) void gemm_as(
    const ushort_t* __restrict__ A, int KP,
    const ushort_t* __restrict__ BH, const ushort_t* __restrict__ BL,
    const float* __restrict__ bias, const float* __restrict__ gg,
    const float* __restrict__ bb, const float* __restrict__ bm,
    const float* __restrict__ bv,
    int Mc, int NnReal, int relu,
    float* __restrict__ outF, int ldF,
    ushort_t* __restrict__ outB, int ldP)
{
    __shared__ ushort_t sA[BMg * 32];    // 16 KB, swizzled quad layout
    __shared__ ushort_t sBH[BNg * 32];   // 4 KB
    __shared__ ushort_t sBL[BNg * 32];   // 4 KB  (total 24 KB)

    const int tid = threadIdx.x;
    const int lane = tid & 63;
    const int w = tid >> 6;
    const int m0 = blockIdx.y * BMg;
    const int n0 = blockIdx.x * BNg;

    const ushort_t* gA[4];
    ushort_t* lA[4];
    const ushort_t* gB[2];
    ushort_t* lB[2];
#pragma unroll
    for (int i = 0; i < 4; ++i) {
        int s = w * 256 + i * 64 + lane;
        int m = s >> 2, qp = s & 3;
        int q = (qp - (m >> 1)) & 3;
        int msrc = (m0 + m < Mc) ? (m0 + m) : (Mc - 1);
        gA[i] = A + (size_t)msrc * KP + 8 * q;
        lA[i] = sA + (w * 256 + i * 64) * 8;
    }
    {
        int s = w * 64 + lane;
        int n = s >> 2, qp = s & 3;
        int q = (qp - (n >> 1)) & 3;
        gB[0] = BH + (size_t)(n0 + n) * KP + 8 * q;
        gB[1] = BL + (size_t)(n0 + n) * KP + 8 * q;
        lB[0] = sBH + (w * 64) * 8;
        lB[1] = sBL + (w * 64) * 8;
    }

    f32x4 acc[4][4];
#pragma unroll
    for (int a = 0; a < 4; ++a)
#pragma unroll
        for (int b = 0; b < 4; ++b) acc[a][b] = (f32x4)(0.f);

    const int q = lane >> 4;
    const int c16 = lane & 15;
    const int kt = KP >> 5;

    for (int t = 0; t < kt; ++t) {
        if (t) __syncthreads();
#pragma unroll
        for (int i = 0; i < 4; ++i) { dma16(gA[i], lA[i]); gA[i] += 32; }
        dma16(gB[0], lB[0]); gB[0] += 32;
        dma16(gB[1], lB[1]); gB[1] += 32;
        __syncthreads();

        short8 av[4], bh[4], bl[4];
#pragma unroll
        for (int tt = 0; tt < 4; ++tt) {
            int m = w * 64 + tt * 16 + c16;
            int q2 = (q + (m >> 1)) & 3;
            av[tt] = *(const short8*)(sA + m * 32 + q2 * 8);
        }
#pragma unroll
        for (int uu = 0; uu < 4; ++uu) {
            int n = uu * 16 + c16;
            int q2 = (q + (n >> 1)) & 3;
            int off = n * 32 + q2 * 8;
            bh[uu] = *(const short8*)(sBH + off);
            bl[uu] = *(const short8*)(sBL + off);
        }
#pragma unroll
        for (int tt = 0; tt < 4; ++tt)
#pragma unroll
            for (int uu = 0; uu < 4; ++uu) {
                acc[tt][uu] = __builtin_amdgcn_mfma_f32_16x16x32_bf16(av[tt], bh[uu], acc[tt][uu], 0, 0, 0);
                acc[tt][uu] = __builtin_amdgcn_mfma_f32_16x16x32_bf16(av[tt], bl[uu], acc[tt][uu], 0, 0, 0);
            }
    }

    // epilogue: C/D layout col=lane&15, row=q*4+r
#pragma unroll
    for (int uu = 0; uu < 4; ++uu) {
        int gn = n0 + uu * 16 + c16;
        float sc = 0.f, sh = 0.f;
        if (gn < NnReal) {
            sc = gg[gn] * rsqrtf(bv[gn] + 1e-5f);
            sh = bb[gn] + (bias[gn] - bm[gn]) * sc;
        }
#pragma unroll
        for (int tt = 0; tt < 4; ++tt) {
            int rbase = m0 + w * 64 + tt * 16 + q * 4;
#pragma unroll
            for (int r = 0; r < 4; ++r) {
                int gm = rbase + r;
                if (gm >= Mc) continue;
                float y = acc[tt][uu][r] * sc + sh;
                if (relu) y = fmaxf(y, 0.f);
                if (outF) {
                    if (gn < NnReal) outF[(size_t)gm * ldF + gn] = y;
                } else {
                    if (gn < ldP) outB[(size_t)gm * ldP + gn] = bf16_of(y);
                }
            }
        }
    }
}

// ---------------- host-side MLP ----------------

struct MlpP {
    const float *b1, *g1, *be1, *m1, *v1;
    const float *b2, *g2, *be2, *m2, *v2;
};

static void run_mlp(hipStream_t stream, const ushort_t* inB, int M,
                    const ushort_t* wh, const ushort_t* wl, int mlp,
                    ushort_t* tB, int CH,
                    const MlpP& W, float* outF, int relu2) {
    const ushort_t* w1h = wh + (size_t)mlp * WPER;
    const ushort_t* w1l = wl + (size_t)mlp * WPER;
    const ushort_t* w2h = w1h + NP1 * KP1;
    const ushort_t* w2l = w1l + NP1 * KP1;
    for (int c0 = 0; c0 < M; c0 += CH) {
        int Mc = (M - c0 < CH) ? (M - c0) : CH;
        {
            dim3 grid(NP1 / BNg, cdiv(Mc, BMg));
            gemm_as<<<grid, 256, 0, stream>>>(
                inB + (size_t)c0 * KP1, KP1, w1h, w1l,
                W.b1, W.g1, W.be1, W.m1, W.v1,
                Mc, 2 * EMBD, 1,
                nullptr, 0, tB, KP2);
        }
        {
            dim3 grid(NP2 / BNg, cdiv(Mc, BMg));
            gemm_as<<<grid, 256, 0, stream>>>(
                tB, KP2, w2h, w2l,
                W.b2, W.g2, W.be2, W.m2, W.v2,
                Mc, EMBD, relu2,
                outF + (size_t)c0 * EMBD, EMBD, nullptr, 0);
        }
    }
}

// ---------------- entry ----------------

extern "C" void kernel_launch(void* const* d_in, const int* in_sizes, int n_in,
                              void* d_out, int out_size, void* d_ws, size_t ws_size,
                              hipStream_t stream) {
    const int*   x        = (const int*)d_in[0];
    const int*   ei       = (const int*)d_in[1];
    const int*   ea       = (const int*)d_in[2];
    const int*   batch    = (const int*)d_in[3];
    const float* atom_emb = (const float*)d_in[4];
    const float* bond_emb = (const float*)d_in[5];
    const float* vn_emb   = (const float*)d_in[6];
    const float* gin_eps  = (const float*)d_in[7];
    const float* gin_W1   = (const float*)d_in[8];
    const float* gin_b1   = (const float*)d_in[9];
    const float* gin_bn1g = (const float*)d_in[10];
    const float* gin_bn1b = (const float*)d_in[11];
    const float* gin_bn1m = (const float*)d_in[12];
    const float* gin_bn1v = (const float*)d_in[13];
    const float* gin_W2   = (const float*)d_in[14];
    const float* gin_b2   = (const float*)d_in[15];
    const float* bn_g     = (const float*)d_in[16];
    const float* bn_b     = (const float*)d_in[17];
    const float* bn_m     = (const float*)d_in[18];
    const float* bn_v     = (const float*)d_in[19];
    const float* vn_W1    = (const float*)d_in[20];
    const float* vn_b1    = (const float*)d_in[21];
    const float* vn_bn1g  = (const float*)d_in[22];
    const float* vn_bn1b  = (const float*)d_in[23];
    const float* vn_bn1m  = (const float*)d_in[24];
    const float* vn_bn1v  = (const float*)d_in[25];
    const float* vn_W2    = (const float*)d_in[26];
    const float* vn_b2    = (const float*)d_in[27];
    const float* vn_bn2g  = (const float*)d_in[28];
    const float* vn_bn2b  = (const float*)d_in[29];
    const float* vn_bn2m  = (const float*)d_in[30];
    const float* vn_bn2v  = (const float*)d_in[31];

    const int N = in_sizes[3];
    const int E = in_sizes[1] / 2;
    const int NB = cdiv(N, 1024);   // scan blocks

    // ---- workspace layout (bytes); fixed ~210 MB of the ~256 MiB budget ----
    char* base = (char*)d_ws;
    size_t off = 0;
    float* hbuf    = (float*)(base + off);    off += (size_t)N * EMBD * 4;   // 120 MB
    ushort_t* aggB = (ushort_t*)(base + off); off += (size_t)N * KP1 * 2;    // 64 MB
    float* vnbuf   = (float*)(base + off);    off += (size_t)GG * EMBD * 4;  // 4.9 MB
    int*   starts  = (int*)(base + off);      off += 4104 * 4;
    int*   cnt     = (int*)(base + off);      off += (size_t)N * 4;
    int*   cursor  = (int*)(base + off);      off += (size_t)N * 4;
    int*   estart  = (int*)(base + off);      off += ((size_t)N + 8) * 4;
    int*   bsum    = (int*)(base + off);      off += 1032 * 4;
    int2*  epack   = (int2*)(base + off);     off += (size_t)E * 8;          // 2 MB
    float* ebsum   = (float*)(base + off);    off += (size_t)512 * EMBD * 4; // 0.6 MB
    ushort_t* whA  = (ushort_t*)(base + off); off += (size_t)9 * WPER * 2;   // 7.4 MB
    ushort_t* wlA  = (ushort_t*)(base + off); off += (size_t)9 * WPER * 2;   // 7.4 MB
    ushort_t* vnaB = (ushort_t*)(base + off); off += (size_t)GG * KP1 * 2;   // 2.6 MB
    off = (off + 255) & ~(size_t)255;

    // adaptive chunk for tB: KP2*2 = 1280 B per row
    size_t avail = (ws_size > off) ? ws_size - off : 0;
    int CH = (int)(avail / (KP2 * 2));
    CH &= ~255;
    if (CH > N) CH = (N + 255) & ~255;
    if (CH < 2048) CH = 2048;  // last resort (slower but correct)
    ushort_t* tB = (ushort_t*)(base + off);

    const int BLK = 256;
    int ne4 = N * 75;

    // ---- one-time init ----
    find_starts<<<cdiv(GG + 1, BLK), BLK, 0, stream>>>(batch, starts, N);
    atom_encode4<<<cdiv(ne4, BLK), BLK, 0, stream>>>(x, atom_emb, hbuf, N);
    init_vn4<<<cdiv(GG * 75, BLK), BLK, 0, stream>>>(vn_emb, vnbuf);
    bond_combo<<<cdiv(512 * EMBD, BLK), BLK, 0, stream>>>(bond_emb, ebsum);
    conv_all<<<cdiv(9 * WPER, BLK), BLK, 0, stream>>>(gin_W1, gin_W2, vn_W1, vn_W2, whA, wlA);
    hipMemsetAsync(cnt, 0, (size_t)N * 4, stream);
    hipMemsetAsync(vnaB, 0, (size_t)GG * KP1 * 2, stream);  // zero pad cols once
    ecount<<<cdiv(E, BLK), BLK, 0, stream>>>(ei, cnt, E);
    scan_part<<<NB, 256, 0, stream>>>(cnt, bsum, N);
    scan_top<<<1, 1024, 0, stream>>>(bsum, NB);
    scan_final<<<NB, 256, 0, stream>>>(cnt, bsum, estart, cursor, N, E);
    escatter<<<cdiv(E, BLK), BLK, 0, stream>>>(ei, ea, cursor, epack, E);

    for (int l = 0; l < NLAY; ++l) {
        int last = (l == NLAY - 1);

        if (!last)
            pool_prep<<<GG, 320, 0, stream>>>(hbuf, vnbuf, starts, vnaB);
        else
            prep_vn<<<cdiv(ne4, BLK), BLK, 0, stream>>>(hbuf, vnbuf, batch, N);

        aggregate<<<cdiv(N, NPB), NPB * 80, 0, stream>>>(
            hbuf, ebsum, estart, epack, gin_eps + l, aggB, N);

        MlpP Wn = { gin_b1 + (size_t)l * 2 * EMBD,
                    gin_bn1g + (size_t)l * 2 * EMBD, gin_bn1b + (size_t)l * 2 * EMBD,
                    gin_bn1m + (size_t)l * 2 * EMBD, gin_bn1v + (size_t)l * 2 * EMBD,
                    gin_b2 + (size_t)l * EMBD,
                    bn_g + (size_t)l * EMBD, bn_b + (size_t)l * EMBD,
                    bn_m + (size_t)l * EMBD, bn_v + (size_t)l * EMBD };
        run_mlp(stream, aggB, N, whA, wlA, l, tB, CH, Wn, hbuf, last ? 0 : 1);

        if (!last) {
            MlpP Wv = { vn_b1 + (size_t)l * 2 * EMBD,
                        vn_bn1g + (size_t)l * 2 * EMBD, vn_bn1b + (size_t)l * 2 * EMBD,
                        vn_bn1m + (size_t)l * 2 * EMBD, vn_bn1v + (size_t)l * 2 * EMBD,
                        vn_b2 + (size_t)l * EMBD,
                        vn_bn2g + (size_t)l * EMBD, vn_bn2b + (size_t)l * EMBD,
                        vn_bn2m + (size_t)l * EMBD, vn_bn2v + (size_t)l * EMBD };
            run_mlp(stream, vnaB, GG, whA, wlA, NLAY + l, tB, CH, Wv, vnbuf, 1);
        }
    }

    pool_mean<<<GG, 320, 0, stream>>>(hbuf, starts, (float*)d_out);
}

// Round 8
// 2206.642 us; speedup vs baseline: 22.4019x; 1.2533x over previous
//
#include <hip/hip_runtime.h>
#include <hip/hip_bf16.h>

#define EMBD 300
#define GG   4096
#define NLAY 5
#define KP1  320   // padded K for EMB=300 inputs (also h row stride)
#define KP2  640   // padded K for 2*EMB=600 inputs
#define NP1  640   // padded out-cols for 600 (5 x 128)
#define NP2  384   // padded out-cols for 300 (3 x 128)
#define WPER (NP1*KP1 + NP2*KP2)   // 450560 elems per MLP weight set

typedef unsigned short ushort_t;
typedef short short8 __attribute__((ext_vector_type(8)));
typedef short short4v __attribute__((ext_vector_type(4)));
typedef float f32x4 __attribute__((ext_vector_type(4)));

static inline int cdiv(int a, int b) { return (a + b - 1) / b; }

// ---------------- helpers ----------------

__device__ inline void dma16(const ushort_t* g, ushort_t* l) {
    __builtin_amdgcn_global_load_lds(
        (const __attribute__((address_space(1))) unsigned int*)g,
        (__attribute__((address_space(3))) unsigned int*)l, 16, 0, 0);
}

__device__ inline void bf16_split(float v, ushort_t& h, ushort_t& l) {
    union { __hip_bfloat16 b; ushort_t u; } c;
    c.b = __float2bfloat16(v);
    h = c.u;
    float hf = __bfloat162float(c.b);
    c.b = __float2bfloat16(v - hf);
    l = c.u;
}

__device__ inline ushort_t bf16_of(float v) {
    union { __hip_bfloat16 b; ushort_t u; } c;
    c.b = __float2bfloat16(v);
    return c.u;
}

__device__ inline float bf2f(ushort_t u) {
    union { unsigned int i; float f; } c;
    c.i = ((unsigned int)u) << 16;
    return c.f;
}

// ---------------- init kernels ----------------

// atom encode -> h bf16 [N][KP1]
__global__ void atom_encode_bf(const int* __restrict__ x, const float* __restrict__ aemb,
                               ushort_t* __restrict__ h, int N) {
    int i = blockIdx.x * blockDim.x + threadIdx.x;
    int total = N * 75;
    if (i >= total) return;
    int n = i / 75, d4 = i - n * 75;
    const int* xr = x + n * 9;
    float4 s = make_float4(0.f, 0.f, 0.f, 0.f);
    const float4* a4 = (const float4*)aemb;
#pragma unroll
    for (int f = 0; f < 9; ++f) {
        float4 v = a4[(size_t)((f << 7) + xr[f]) * 75 + d4];
        s.x += v.x; s.y += v.y; s.z += v.z; s.w += v.w;
    }
    short4v o;
    o[0] = (short)bf16_of(s.x); o[1] = (short)bf16_of(s.y);
    o[2] = (short)bf16_of(s.z); o[3] = (short)bf16_of(s.w);
    *(short4v*)(h + (size_t)n * KP1 + d4 * 4) = o;
}

__global__ void init_vn4(const float* __restrict__ vn_emb, float* __restrict__ vn) {
    int i = blockIdx.x * blockDim.x + threadIdx.x;
    if (i >= GG * 75) return;
    ((float4*)vn)[i] = ((const float4*)vn_emb)[i % 75];
}

__global__ void find_starts(const int* __restrict__ batch, int* __restrict__ starts, int N) {
    int g = blockIdx.x * blockDim.x + threadIdx.x;
    if (g > GG) return;
    int lo = 0, hi = N;
    while (lo < hi) {
        int mid = (lo + hi) >> 1;
        if (batch[mid] < g) lo = mid + 1; else hi = mid;
    }
    starts[g] = lo;
}

// bond combo table: ebsum[c][d], c=(a0<<6)|(a1<<3)|a2
__global__ void bond_combo(const float* __restrict__ bemb, float* __restrict__ ebsum) {
    int i = blockIdx.x * blockDim.x + threadIdx.x;
    if (i >= 512 * EMBD) return;
    int c = i / EMBD, d = i - c * EMBD;
    int a0 = c >> 6, a1 = (c >> 3) & 7, a2 = c & 7;
    ebsum[i] = bemb[a0 * EMBD + d] + bemb[(8 + a1) * EMBD + d] + bemb[(16 + a2) * EMBD + d];
}

// convert all 9 MLP weight sets into transposed split-bf16 planes
__global__ void conv_all(const float* __restrict__ gW1, const float* __restrict__ gW2,
                         const float* __restrict__ vW1, const float* __restrict__ vW2,
                         ushort_t* __restrict__ wh, ushort_t* __restrict__ wl) {
    int i = blockIdx.x * blockDim.x + threadIdx.x;
    int total = WPER * 9;
    if (i >= total) return;
    int mlp = i / WPER, r = i - mlp * WPER;
    const float *W1, *W2;
    if (mlp < NLAY) {
        W1 = gW1 + (size_t)mlp * EMBD * 2 * EMBD;
        W2 = gW2 + (size_t)mlp * 2 * EMBD * EMBD;
    } else {
        int l = mlp - NLAY;
        W1 = vW1 + (size_t)l * EMBD * 2 * EMBD;
        W2 = vW2 + (size_t)l * 2 * EMBD * EMBD;
    }
    float v;
    if (r < NP1 * KP1) {
        int n = r / KP1, k = r - n * KP1;
        v = (n < 2 * EMBD && k < EMBD) ? W1[(size_t)k * (2 * EMBD) + n] : 0.f;
    } else {
        int r2 = r - NP1 * KP1;
        int n = r2 / KP2, k = r2 - n * KP2;
        v = (n < EMBD && k < 2 * EMBD) ? W2[(size_t)k * EMBD + n] : 0.f;
    }
    ushort_t hh, ll;
    bf16_split(v, hh, ll);
    wh[i] = hh;
    wl[i] = ll;
}

// ---------------- edge bucket sort ----------------

__global__ void ecount(const int* __restrict__ ei, int* __restrict__ cnt, int E) {
    int e = blockIdx.x * blockDim.x + threadIdx.x;
    if (e >= E) return;
    atomicAdd(&cnt[ei[E + e]], 1);
}

__global__ void scan_part(const int* __restrict__ cnt, int* __restrict__ bsum, int N) {
    __shared__ int sh[256];
    int b = blockIdx.x, t = threadIdx.x;
    int base = b * 1024;
    int s = 0;
    for (int j = t; j < 1024; j += 256) {
        int idx = base + j;
        if (idx < N) s += cnt[idx];
    }
    sh[t] = s;
    __syncthreads();
    for (int d = 128; d > 0; d >>= 1) {
        if (t < d) sh[t] += sh[t + d];
        __syncthreads();
    }
    if (t == 0) bsum[b] = sh[0];
}

__global__ void scan_top(int* __restrict__ bsum, int nb) {
    __shared__ int sh[1024];
    int t = threadIdx.x;
    int v = (t < nb) ? bsum[t] : 0;
    sh[t] = v;
    __syncthreads();
    for (int d = 1; d < 1024; d <<= 1) {
        int u = (t >= d) ? sh[t - d] : 0;
        __syncthreads();
        sh[t] += u;
        __syncthreads();
    }
    if (t < nb) bsum[t] = sh[t] - v;  // exclusive
}

__global__ void scan_final(const int* __restrict__ cnt, const int* __restrict__ bsum,
                           int* __restrict__ estart, int* __restrict__ cursor, int N, int E) {
    __shared__ int sh[256];
    int b = blockIdx.x, t = threadIdx.x;
    int base = b * 1024 + t * 4;
    int c[4];
    int s = 0;
#pragma unroll
    for (int j = 0; j < 4; ++j) {
        int idx = base + j;
        c[j] = (idx < N) ? cnt[idx] : 0;
        s += c[j];
    }
    sh[t] = s;
    __syncthreads();
    for (int d = 1; d < 256; d <<= 1) {
        int u = (t >= d) ? sh[t - d] : 0;
        __syncthreads();
        sh[t] += u;
        __syncthreads();
    }
    int run = sh[t] - s + bsum[b];
#pragma unroll
    for (int j = 0; j < 4; ++j) {
        int idx = base + j;
        if (idx < N) { estart[idx] = run; cursor[idx] = run; run += c[j]; }
    }
    if (b == 0 && t == 0) estart[N] = E;
}

__global__ void escatter(const int* __restrict__ ei, const int* __restrict__ ea,
                         int* __restrict__ cursor, int2* __restrict__ epack, int E) {
    int e = blockIdx.x * blockDim.x + threadIdx.x;
    if (e >= E) return;
    int c = ei[E + e];
    int p = atomicAdd(&cursor[c], 1);
    epack[p] = make_int2(ei[e], (ea[3 * e] << 6) | (ea[3 * e + 1] << 3) | ea[3 * e + 2]);
}

// ---------------- fused per-layer elementwise (h is bf16 [N][KP1]) ----------------

// non-last: h[n] += vn[g] in place (bf16); vnaB[g] = bf16(segment_sum(h_new) + vn[g])
__global__ void pool_prep(ushort_t* __restrict__ h, const float* __restrict__ vn,
                          const int* __restrict__ starts, ushort_t* __restrict__ vnaB) {
    int g = blockIdx.x;
    int t = threadIdx.x;   // 320
    if (t >= EMBD) return;
    float vng = vn[(size_t)g * EMBD + t];
    int s0 = starts[g], s1 = starts[g + 1];
    float s = 0.f;
    for (int n = s0; n < s1; ++n) {
        size_t idx = (size_t)n * KP1 + t;
        float v = bf2f(h[idx]) + vng;
        h[idx] = bf16_of(v);
        s += v;
    }
    vnaB[(size_t)g * KP1 + t] = bf16_of(s + vng);
}

// last layer: h += vn[batch] only
__global__ void prep_vn(ushort_t* __restrict__ h, const float* __restrict__ vn,
                        const int* __restrict__ batch, int N) {
    int i = blockIdx.x * blockDim.x + threadIdx.x;
    int total = N * 75;
    if (i >= total) return;
    int n = i / 75, d4 = i - n * 75;
    float4 vv = ((const float4*)vn)[(size_t)batch[n] * 75 + d4];
    short4v hv = *(short4v*)(h + (size_t)n * KP1 + d4 * 4);
    short4v o;
    o[0] = (short)bf16_of(bf2f((ushort_t)hv[0]) + vv.x);
    o[1] = (short)bf16_of(bf2f((ushort_t)hv[1]) + vv.y);
    o[2] = (short)bf16_of(bf2f((ushort_t)hv[2]) + vv.z);
    o[3] = (short)bf16_of(bf2f((ushort_t)hv[3]) + vv.w);
    *(short4v*)(h + (size_t)n * KP1 + d4 * 4) = o;
}

__global__ void pool_mean(const ushort_t* __restrict__ h, const int* __restrict__ starts,
                          float* __restrict__ out) {
    int g = blockIdx.x;
    int t = threadIdx.x;
    if (t >= EMBD) return;
    int s0 = starts[g], s1 = starts[g + 1];
    float s = 0.f;
    for (int n = s0; n < s1; ++n) s += bf2f(h[(size_t)n * KP1 + t]);
    float cnt = (float)(s1 - s0);
    out[(size_t)g * EMBD + t] = s / fmaxf(cnt, 1.0f);
}

// ---------------- fused aggregate: (1+eps)h + sum relu(h[src]+bondsum) -> bf16 ----------------
#define NPB 4   // nodes per block; blockDim = NPB*80 = 320

__global__ void aggregate(const ushort_t* __restrict__ h, const float* __restrict__ ebsum,
                          const int* __restrict__ estart, const int2* __restrict__ epack,
                          const float* __restrict__ epsp,
                          ushort_t* __restrict__ aggB, int N) {
    int n = blockIdx.x * NPB + threadIdx.x / 80;
    int slot = threadIdx.x % 80;
    if (n >= N) return;
    float4 acc = make_float4(0.f, 0.f, 0.f, 0.f);
    if (slot < 75) {
        const float4* b4 = (const float4*)ebsum;
        float ce = 1.0f + *epsp;
        short4v hv = *(const short4v*)(h + (size_t)n * KP1 + slot * 4);
        acc.x = ce * bf2f((ushort_t)hv[0]);
        acc.y = ce * bf2f((ushort_t)hv[1]);
        acc.z = ce * bf2f((ushort_t)hv[2]);
        acc.w = ce * bf2f((ushort_t)hv[3]);
        int p0 = estart[n], p1 = estart[n + 1];
        for (int p = p0; p < p1; ++p) {
            int2 ep = epack[p];
            short4v xv = *(const short4v*)(h + (size_t)ep.x * KP1 + slot * 4);
            float4 ev = b4[(size_t)ep.y * 75 + slot];
            acc.x += fmaxf(bf2f((ushort_t)xv[0]) + ev.x, 0.f);
            acc.y += fmaxf(bf2f((ushort_t)xv[1]) + ev.y, 0.f);
            acc.z += fmaxf(bf2f((ushort_t)xv[2]) + ev.z, 0.f);
            acc.w += fmaxf(bf2f((ushort_t)xv[3]) + ev.w, 0.f);
        }
    }
    short4v bv4;
    bv4[0] = (short)bf16_of(acc.x);
    bv4[1] = (short)bf16_of(acc.y);
    bv4[2] = (short)bf16_of(acc.z);
    bv4[3] = (short)bf16_of(acc.w);
    *(short4v*)(aggB + (size_t)n * KP1 + slot * 4) = bv4;
}

// ---------------- MFMA GEMM: 128x128 tile, XCD-swizzled 1D grid ----------------
#define BMg 128
#define BNg 128

__global__ __launch_bounds__(256) void gemm_as(
    const ushort_t* __restrict__ A, int KP,
    const ushort_t* __restrict__ BH, const ushort_t* __restrict__ BL,
    const float* __restrict__ bias, const float* __restrict__ gg,
    const float* __restrict__ bb, const float* __restrict__ bm,
    const float* __restrict__ bv,
    int Mc, int NnReal, int relu, int nb, int mb,
    float* __restrict__ outF, int ldF,
    ushort_t* __restrict__ outB, int ldP)
{
    __shared__ ushort_t sA[BMg * 32];    // 8 KB each, 24 KB total
    __shared__ ushort_t sBH[BNg * 32];
    __shared__ ushort_t sBL[BNg * 32];

    // XCD-aware swizzle: blocks with the same m-strip run consecutively on one XCD
    // (dispatch round-robins id%8 across XCDs; n varies fastest within an XCD)
    {
    }
    int id = blockIdx.x;
    int hi = id / (8 * nb);
    int rem = id - hi * 8 * nb;
    int xcd = rem & 7;
    int nblk = rem >> 3;
    int mblk = hi * 8 + xcd;
    if (mblk >= mb) return;

    const int tid = threadIdx.x;
    const int lane = tid & 63;
    const int w = tid >> 6;
    const int m0 = mblk * BMg;
    const int n0 = nblk * BNg;
    const int wm = (w & 1) * 64;
    const int wn = (w >> 1) * 64;

    // DMA slots: s = row*4 + q'; q' = (q + (row>>1)) & 3 swizzle; LDS base wave-uniform.
    const ushort_t* gA[2];
    const ushort_t* gBH[2];
    const ushort_t* gBL[2];
    int lbase[2];
#pragma unroll
    for (int i = 0; i < 2; ++i) {
        int s = tid + 256 * i;
        int m = s >> 2, qp = s & 3;
        int q = (qp - (m >> 1)) & 3;
        int msrc = (m0 + m < Mc) ? (m0 + m) : (Mc - 1);
        gA[i]  = A + (size_t)msrc * KP + 8 * q;
        gBH[i] = BH + (size_t)(n0 + m) * KP + 8 * q;  // B rows fully padded
        gBL[i] = BL + (size_t)(n0 + m) * KP + 8 * q;
        lbase[i] = (w * 64 + 256 * i) * 8;
    }

    f32x4 acc[4][4];
#pragma unroll
    for (int a = 0; a < 4; ++a)
#pragma unroll
        for (int b = 0; b < 4; ++b) acc[a][b] = (f32x4)(0.f);

    const int q = lane >> 4;
    const int c16 = lane & 15;
    const int kt = KP >> 5;

    for (int t = 0; t < kt; ++t) {
        if (t) __syncthreads();
#pragma unroll
        for (int i = 0; i < 2; ++i) {
            dma16(gA[i],  sA  + lbase[i]); gA[i]  += 32;
            dma16(gBH[i], sBH + lbase[i]); gBH[i] += 32;
            dma16(gBL[i], sBL + lbase[i]); gBL[i] += 32;
        }
        __syncthreads();

        short8 av[4], bh[4], bl[4];
#pragma unroll
        for (int tt = 0; tt < 4; ++tt) {
            int m = wm + tt * 16 + c16;
            int q2 = (q + (m >> 1)) & 3;
            av[tt] = *(const short8*)(sA + m * 32 + q2 * 8);
        }
#pragma unroll
        for (int uu = 0; uu < 4; ++uu) {
            int n = wn + uu * 16 + c16;
            int q2 = (q + (n >> 1)) & 3;
            int off = n * 32 + q2 * 8;
            bh[uu] = *(const short8*)(sBH + off);
            bl[uu] = *(const short8*)(sBL + off);
        }
#pragma unroll
        for (int tt = 0; tt < 4; ++tt)
#pragma unroll
            for (int uu = 0; uu < 4; ++uu) {
                acc[tt][uu] = __builtin_amdgcn_mfma_f32_16x16x32_bf16(av[tt], bh[uu], acc[tt][uu], 0, 0, 0);
                acc[tt][uu] = __builtin_amdgcn_mfma_f32_16x16x32_bf16(av[tt], bl[uu], acc[tt][uu], 0, 0, 0);
            }
    }

    // epilogue: C/D layout col=lane&15, row=q*4+r
#pragma unroll
    for (int uu = 0; uu < 4; ++uu) {
        int gn = n0 + wn + uu * 16 + c16;
        float sc = 0.f, sh = 0.f;
        if (gn < NnReal) {
            sc = gg[gn] * rsqrtf(bv[gn] + 1e-5f);
            sh = bb[gn] + (bias[gn] - bm[gn]) * sc;
        }
#pragma unroll
        for (int tt = 0; tt < 4; ++tt) {
            int rbase = m0 + wm + tt * 16 + q * 4;
#pragma unroll
            for (int r = 0; r < 4; ++r) {
                int gm = rbase + r;
                if (gm >= Mc) continue;
                float y = acc[tt][uu][r] * sc + sh;
                if (relu) y = fmaxf(y, 0.f);
                if (outF) {
                    if (gn < NnReal) outF[(size_t)gm * ldF + gn] = y;
                } else {
                    if (gn < ldP) outB[(size_t)gm * ldP + gn] = bf16_of(y);
                }
            }
        }
    }
}

// ---------------- host-side MLP ----------------

struct MlpP {
    const float *b1, *g1, *be1, *m1, *v1;
    const float *b2, *g2, *be2, *m2, *v2;
};

static void run_mlp(hipStream_t stream, const ushort_t* inB, int M,
                    const ushort_t* wh, const ushort_t* wl, int mlp,
                    ushort_t* tB, int CH,
                    const MlpP& W, ushort_t* outB, int relu2) {
    const ushort_t* w1h = wh + (size_t)mlp * WPER;
    const ushort_t* w1l = wl + (size_t)mlp * WPER;
    const ushort_t* w2h = w1h + NP1 * KP1;
    const ushort_t* w2l = w1l + NP1 * KP1;
    for (int c0 = 0; c0 < M; c0 += CH) {
        int Mc = (M - c0 < CH) ? (M - c0) : CH;
        int mb = cdiv(Mc, BMg);
        int mbp = cdiv(mb, 8) * 8;
        {
            int nb = NP1 / BNg;   // 5
            gemm_as<<<nb * mbp, 256, 0, stream>>>(
                inB + (size_t)c0 * KP1, KP1, w1h, w1l,
                W.b1, W.g1, W.be1, W.m1, W.v1,
                Mc, 2 * EMBD, 1, nb, mb,
                nullptr, 0, tB, KP2);
        }
        {
            int nb = NP2 / BNg;   // 3
            gemm_as<<<nb * mbp, 256, 0, stream>>>(
                tB, KP2, w2h, w2l,
                W.b2, W.g2, W.be2, W.m2, W.v2,
                Mc, EMBD, relu2, nb, mb,
                nullptr, 0, outB + (size_t)c0 * KP1, KP1);
        }
    }
}

// ---------------- entry ----------------

extern "C" void kernel_launch(void* const* d_in, const int* in_sizes, int n_in,
                              void* d_out, int out_size, void* d_ws, size_t ws_size,
                              hipStream_t stream) {
    const int*   x        = (const int*)d_in[0];
    const int*   ei       = (const int*)d_in[1];
    const int*   ea       = (const int*)d_in[2];
    const int*   batch    = (const int*)d_in[3];
    const float* atom_emb = (const float*)d_in[4];
    const float* bond_emb = (const float*)d_in[5];
    const float* vn_emb   = (const float*)d_in[6];
    const float* gin_eps  = (const float*)d_in[7];
    const float* gin_W1   = (const float*)d_in[8];
    const float* gin_b1   = (const float*)d_in[9];
    const float* gin_bn1g = (const float*)d_in[10];
    const float* gin_bn1b = (const float*)d_in[11];
    const float* gin_bn1m = (const float*)d_in[12];
    const float* gin_bn1v = (const float*)d_in[13];
    const float* gin_W2   = (const float*)d_in[14];
    const float* gin_b2   = (const float*)d_in[15];
    const float* bn_g     = (const float*)d_in[16];
    const float* bn_b     = (const float*)d_in[17];
    const float* bn_m     = (const float*)d_in[18];
    const float* bn_v     = (const float*)d_in[19];
    const float* vn_W1    = (const float*)d_in[20];
    const float* vn_b1    = (const float*)d_in[21];
    const float* vn_bn1g  = (const float*)d_in[22];
    const float* vn_bn1b  = (const float*)d_in[23];
    const float* vn_bn1m  = (const float*)d_in[24];
    const float* vn_bn1v  = (const float*)d_in[25];
    const float* vn_W2    = (const float*)d_in[26];
    const float* vn_b2    = (const float*)d_in[27];
    const float* vn_bn2g  = (const float*)d_in[28];
    const float* vn_bn2b  = (const float*)d_in[29];
    const float* vn_bn2m  = (const float*)d_in[30];
    const float* vn_bn2v  = (const float*)d_in[31];

    const int N = in_sizes[3];
    const int E = in_sizes[1] / 2;
    const int NB = cdiv(N, 1024);

    // ---- workspace layout (bytes); fixed ~155 MB of the ~256 MiB budget ----
    char* base = (char*)d_ws;
    size_t off = 0;
    ushort_t* hbuf = (ushort_t*)(base + off); off += (size_t)N * KP1 * 2;    // 64 MB (bf16 h)
    ushort_t* aggB = (ushort_t*)(base + off); off += (size_t)N * KP1 * 2;    // 64 MB
    float* vnbuf   = (float*)(base + off);    off += (size_t)GG * EMBD * 4;  // 4.9 MB
    int*   starts  = (int*)(base + off);      off += 4104 * 4;
    int*   cnt     = (int*)(base + off);      off += (size_t)N * 4;
    int*   cursor  = (int*)(base + off);      off += (size_t)N * 4;
    int*   estart  = (int*)(base + off);      off += ((size_t)N + 8) * 4;
    int*   bsum    = (int*)(base + off);      off += 1032 * 4;
    int2*  epack   = (int2*)(base + off);     off += (size_t)E * 8;          // 2 MB
    float* ebsum   = (float*)(base + off);    off += (size_t)512 * EMBD * 4; // 0.6 MB
    ushort_t* whA  = (ushort_t*)(base + off); off += (size_t)9 * WPER * 2;   // 8.1 MB
    ushort_t* wlA  = (ushort_t*)(base + off); off += (size_t)9 * WPER * 2;   // 8.1 MB
    ushort_t* vnaB = (ushort_t*)(base + off); off += (size_t)GG * KP1 * 2;   // 2.6 MB
    off = (off + 255) & ~(size_t)255;

    // adaptive chunk for tB: KP2*2 = 1280 B per row; balance if 2 chunks
    size_t avail = (ws_size > off) ? ws_size - off : 0;
    int CH = (int)(avail / (KP2 * 2));
    CH &= ~255;
    if (CH > N) CH = (N + 255) & ~255;
    else if (CH >= (N + 1) / 2) CH = (((N + 1) / 2) + 255) & ~255;   // 2 balanced chunks
    if (CH < 2048) CH = 2048;  // last resort
    ushort_t* tB = (ushort_t*)(base + off);

    const int BLK = 256;
    int ne4 = N * 75;

    // ---- one-time init ----
    find_starts<<<cdiv(GG + 1, BLK), BLK, 0, stream>>>(batch, starts, N);
    atom_encode_bf<<<cdiv(ne4, BLK), BLK, 0, stream>>>(x, atom_emb, hbuf, N);
    init_vn4<<<cdiv(GG * 75, BLK), BLK, 0, stream>>>(vn_emb, vnbuf);
    bond_combo<<<cdiv(512 * EMBD, BLK), BLK, 0, stream>>>(bond_emb, ebsum);
    conv_all<<<cdiv(9 * WPER, BLK), BLK, 0, stream>>>(gin_W1, gin_W2, vn_W1, vn_W2, whA, wlA);
    hipMemsetAsync(cnt, 0, (size_t)N * 4, stream);
    hipMemsetAsync(vnaB, 0, (size_t)GG * KP1 * 2, stream);  // zero pad cols (runs every call)
    ecount<<<cdiv(E, BLK), BLK, 0, stream>>>(ei, cnt, E);
    scan_part<<<NB, 256, 0, stream>>>(cnt, bsum, N);
    scan_top<<<1, 1024, 0, stream>>>(bsum, NB);
    scan_final<<<NB, 256, 0, stream>>>(cnt, bsum, estart, cursor, N, E);
    escatter<<<cdiv(E, BLK), BLK, 0, stream>>>(ei, ea, cursor, epack, E);

    for (int l = 0; l < NLAY; ++l) {
        int last = (l == NLAY - 1);

        if (!last)
            pool_prep<<<GG, 320, 0, stream>>>(hbuf, vnbuf, starts, vnaB);
        else
            prep_vn<<<cdiv(ne4, BLK), BLK, 0, stream>>>(hbuf, vnbuf, batch, N);

        aggregate<<<cdiv(N, NPB), NPB * 80, 0, stream>>>(
            hbuf, ebsum, estart, epack, gin_eps + l, aggB, N);

        MlpP Wn = { gin_b1 + (size_t)l * 2 * EMBD,
                    gin_bn1g + (size_t)l * 2 * EMBD, gin_bn1b + (size_t)l * 2 * EMBD,
                    gin_bn1m + (size_t)l * 2 * EMBD, gin_bn1v + (size_t)l * 2 * EMBD,
                    gin_b2 + (size_t)l * EMBD,
                    bn_g + (size_t)l * EMBD, bn_b + (size_t)l * EMBD,
                    bn_m + (size_t)l * EMBD, bn_v + (size_t)l * EMBD };
        run_mlp(stream, aggB, N, whA, wlA, l, tB, CH, Wn, hbuf, last ? 0 : 1);

        if (!last) {
            MlpP Wv = { vn_b1 + (size_t)l * 2 * EMBD,
                        vn_bn1g + (size_t)l * 2 * EMBD, vn_bn1b + (size_t)l * 2 * EMBD,
                        vn_bn1m + (size_t)l * 2 * EMBD, vn_bn1v + (size_t)l * 2 * EMBD,
                        vn_b2 + (size_t)l * EMBD,
                        vn_bn2g + (size_t)l * EMBD, vn_bn2b + (size_t)l * EMBD,
                        vn_bn2m + (size_t)l * EMBD, vn_bn2v + (size_t)l * EMBD };
            // vn MLP output must be fp32 (vnbuf) -> use outF path via a tiny wrapper:
            // reuse gemm_as with outF for GEMM2 by calling directly
            const ushort_t* w1h = whA + (size_t)(NLAY + l) * WPER;
            const ushort_t* w1l = wlA + (size_t)(NLAY + l) * WPER;
            const ushort_t* w2h = w1h + NP1 * KP1;
            const ushort_t* w2l = w1l + NP1 * KP1;
            int mb = cdiv(GG, BMg), mbp = cdiv(mb, 8) * 8;
            gemm_as<<<(NP1 / BNg) * mbp, 256, 0, stream>>>(
                vnaB, KP1, w1h, w1l,
                Wv.b1, Wv.g1, Wv.be1, Wv.m1, Wv.v1,
                GG, 2 * EMBD, 1, NP1 / BNg, mb,
                nullptr, 0, tB, KP2);
            gemm_as<<<(NP2 / BNg) * mbp, 256, 0, stream>>>(
                tB, KP2, w2h, w2l,
                Wv.b2, Wv.g2, Wv.be2, Wv.m2, Wv.v2,
                GG, EMBD, 1, NP2 / BNg, mb,
                vnbuf, EMBD, nullptr, 0);
        }
    }

    pool_mean<<<GG, 320, 0, stream>>>(hbuf, starts, (float*)d_out);
}

// Round 9
// 1932.693 us; speedup vs baseline: 25.5772x; 1.1417x over previous
//
#include <hip/hip_runtime.h>
#include <hip/hip_bf16.h>

#define EMBD 300
#define GG   4096
#define NLAY 5
#define KP1  320   // padded K for EMB=300 inputs (also h row stride)
#define KP2  640   // padded K for 2*EMB=600 inputs
#define NP1  640   // padded out-cols for 600 (5 x 128)
#define NP2  384   // padded out-cols for 300 (3 x 128)
#define WPER (NP1*KP1 + NP2*KP2)   // 450560 elems per MLP weight set

typedef unsigned short ushort_t;
typedef short short8 __attribute__((ext_vector_type(8)));
typedef short short4v __attribute__((ext_vector_type(4)));
typedef float f32x4 __attribute__((ext_vector_type(4)));

static inline int cdiv(int a, int b) { return (a + b - 1) / b; }

// ---------------- helpers ----------------

__device__ inline void dma16(const ushort_t* g, ushort_t* l) {
    __builtin_amdgcn_global_load_lds(
        (const __attribute__((address_space(1))) unsigned int*)g,
        (__attribute__((address_space(3))) unsigned int*)l, 16, 0, 0);
}

__device__ inline ushort_t bf16_of(float v) {
    union { __hip_bfloat16 b; ushort_t u; } c;
    c.b = __float2bfloat16(v);
    return c.u;
}

__device__ inline float bf2f(ushort_t u) {
    union { unsigned int i; float f; } c;
    c.i = ((unsigned int)u) << 16;
    return c.f;
}

// ---------------- init kernels ----------------

// atom encode -> h bf16 [N][KP1]
__global__ void atom_encode_bf(const int* __restrict__ x, const float* __restrict__ aemb,
                               ushort_t* __restrict__ h, int N) {
    int i = blockIdx.x * blockDim.x + threadIdx.x;
    int total = N * 75;
    if (i >= total) return;
    int n = i / 75, d4 = i - n * 75;
    const int* xr = x + n * 9;
    float4 s = make_float4(0.f, 0.f, 0.f, 0.f);
    const float4* a4 = (const float4*)aemb;
#pragma unroll
    for (int f = 0; f < 9; ++f) {
        float4 v = a4[(size_t)((f << 7) + xr[f]) * 75 + d4];
        s.x += v.x; s.y += v.y; s.z += v.z; s.w += v.w;
    }
    short4v o;
    o[0] = (short)bf16_of(s.x); o[1] = (short)bf16_of(s.y);
    o[2] = (short)bf16_of(s.z); o[3] = (short)bf16_of(s.w);
    *(short4v*)(h + (size_t)n * KP1 + d4 * 4) = o;
}

__global__ void init_vn4(const float* __restrict__ vn_emb, float* __restrict__ vn) {
    int i = blockIdx.x * blockDim.x + threadIdx.x;
    if (i >= GG * 75) return;
    ((float4*)vn)[i] = ((const float4*)vn_emb)[i % 75];
}

__global__ void find_starts(const int* __restrict__ batch, int* __restrict__ starts, int N) {
    int g = blockIdx.x * blockDim.x + threadIdx.x;
    if (g > GG) return;
    int lo = 0, hi = N;
    while (lo < hi) {
        int mid = (lo + hi) >> 1;
        if (batch[mid] < g) lo = mid + 1; else hi = mid;
    }
    starts[g] = lo;
}

// bond combo table: ebsum[c][d], c=(a0<<6)|(a1<<3)|a2
__global__ void bond_combo(const float* __restrict__ bemb, float* __restrict__ ebsum) {
    int i = blockIdx.x * blockDim.x + threadIdx.x;
    if (i >= 512 * EMBD) return;
    int c = i / EMBD, d = i - c * EMBD;
    int a0 = c >> 6, a1 = (c >> 3) & 7, a2 = c & 7;
    ebsum[i] = bemb[a0 * EMBD + d] + bemb[(8 + a1) * EMBD + d] + bemb[(16 + a2) * EMBD + d];
}

// convert all 9 MLP weight sets into transposed single-bf16 planes
__global__ void conv_all(const float* __restrict__ gW1, const float* __restrict__ gW2,
                         const float* __restrict__ vW1, const float* __restrict__ vW2,
                         ushort_t* __restrict__ wh) {
    int i = blockIdx.x * blockDim.x + threadIdx.x;
    int total = WPER * 9;
    if (i >= total) return;
    int mlp = i / WPER, r = i - mlp * WPER;
    const float *W1, *W2;
    if (mlp < NLAY) {
        W1 = gW1 + (size_t)mlp * EMBD * 2 * EMBD;
        W2 = gW2 + (size_t)mlp * 2 * EMBD * EMBD;
    } else {
        int l = mlp - NLAY;
        W1 = vW1 + (size_t)l * EMBD * 2 * EMBD;
        W2 = vW2 + (size_t)l * 2 * EMBD * EMBD;
    }
    float v;
    if (r < NP1 * KP1) {
        int n = r / KP1, k = r - n * KP1;
        v = (n < 2 * EMBD && k < EMBD) ? W1[(size_t)k * (2 * EMBD) + n] : 0.f;
    } else {
        int r2 = r - NP1 * KP1;
        int n = r2 / KP2, k = r2 - n * KP2;
        v = (n < EMBD && k < 2 * EMBD) ? W2[(size_t)k * EMBD + n] : 0.f;
    }
    wh[i] = bf16_of(v);
}

// ---------------- edge bucket sort ----------------

__global__ void ecount(const int* __restrict__ ei, int* __restrict__ cnt, int E) {
    int e = blockIdx.x * blockDim.x + threadIdx.x;
    if (e >= E) return;
    atomicAdd(&cnt[ei[E + e]], 1);
}

__global__ void scan_part(const int* __restrict__ cnt, int* __restrict__ bsum, int N) {
    __shared__ int sh[256];
    int b = blockIdx.x, t = threadIdx.x;
    int base = b * 1024;
    int s = 0;
    for (int j = t; j < 1024; j += 256) {
        int idx = base + j;
        if (idx < N) s += cnt[idx];
    }
    sh[t] = s;
    __syncthreads();
    for (int d = 128; d > 0; d >>= 1) {
        if (t < d) sh[t] += sh[t + d];
        __syncthreads();
    }
    if (t == 0) bsum[b] = sh[0];
}

__global__ void scan_top(int* __restrict__ bsum, int nb) {
    __shared__ int sh[1024];
    int t = threadIdx.x;
    int v = (t < nb) ? bsum[t] : 0;
    sh[t] = v;
    __syncthreads();
    for (int d = 1; d < 1024; d <<= 1) {
        int u = (t >= d) ? sh[t - d] : 0;
        __syncthreads();
        sh[t] += u;
        __syncthreads();
    }
    if (t < nb) bsum[t] = sh[t] - v;  // exclusive
}

__global__ void scan_final(const int* __restrict__ cnt, const int* __restrict__ bsum,
                           int* __restrict__ estart, int* __restrict__ cursor, int N, int E) {
    __shared__ int sh[256];
    int b = blockIdx.x, t = threadIdx.x;
    int base = b * 1024 + t * 4;
    int c[4];
    int s = 0;
#pragma unroll
    for (int j = 0; j < 4; ++j) {
        int idx = base + j;
        c[j] = (idx < N) ? cnt[idx] : 0;
        s += c[j];
    }
    sh[t] = s;
    __syncthreads();
    for (int d = 1; d < 256; d <<= 1) {
        int u = (t >= d) ? sh[t - d] : 0;
        __syncthreads();
        sh[t] += u;
        __syncthreads();
    }
    int run = sh[t] - s + bsum[b];
#pragma unroll
    for (int j = 0; j < 4; ++j) {
        int idx = base + j;
        if (idx < N) { estart[idx] = run; cursor[idx] = run; run += c[j]; }
    }
    if (b == 0 && t == 0) estart[N] = E;
}

__global__ void escatter(const int* __restrict__ ei, const int* __restrict__ ea,
                         int* __restrict__ cursor, int2* __restrict__ epack, int E) {
    int e = blockIdx.x * blockDim.x + threadIdx.x;
    if (e >= E) return;
    int c = ei[E + e];
    int p = atomicAdd(&cursor[c], 1);
    epack[p] = make_int2(ei[e], (ea[3 * e] << 6) | (ea[3 * e + 1] << 3) | ea[3 * e + 2]);
}

// ---------------- fused per-layer elementwise (h is bf16 [N][KP1]) ----------------

__global__ void pool_prep(ushort_t* __restrict__ h, const float* __restrict__ vn,
                          const int* __restrict__ starts, ushort_t* __restrict__ vnaB) {
    int g = blockIdx.x;
    int t = threadIdx.x;   // 320
    if (t >= EMBD) return;
    float vng = vn[(size_t)g * EMBD + t];
    int s0 = starts[g], s1 = starts[g + 1];
    float s = 0.f;
    for (int n = s0; n < s1; ++n) {
        size_t idx = (size_t)n * KP1 + t;
        float v = bf2f(h[idx]) + vng;
        h[idx] = bf16_of(v);
        s += v;
    }
    vnaB[(size_t)g * KP1 + t] = bf16_of(s + vng);
}

__global__ void prep_vn(ushort_t* __restrict__ h, const float* __restrict__ vn,
                        const int* __restrict__ batch, int N) {
    int i = blockIdx.x * blockDim.x + threadIdx.x;
    int total = N * 75;
    if (i >= total) return;
    int n = i / 75, d4 = i - n * 75;
    float4 vv = ((const float4*)vn)[(size_t)batch[n] * 75 + d4];
    short4v hv = *(short4v*)(h + (size_t)n * KP1 + d4 * 4);
    short4v o;
    o[0] = (short)bf16_of(bf2f((ushort_t)hv[0]) + vv.x);
    o[1] = (short)bf16_of(bf2f((ushort_t)hv[1]) + vv.y);
    o[2] = (short)bf16_of(bf2f((ushort_t)hv[2]) + vv.z);
    o[3] = (short)bf16_of(bf2f((ushort_t)hv[3]) + vv.w);
    *(short4v*)(h + (size_t)n * KP1 + d4 * 4) = o;
}

__global__ void pool_mean(const ushort_t* __restrict__ h, const int* __restrict__ starts,
                          float* __restrict__ out) {
    int g = blockIdx.x;
    int t = threadIdx.x;
    if (t >= EMBD) return;
    int s0 = starts[g], s1 = starts[g + 1];
    float s = 0.f;
    for (int n = s0; n < s1; ++n) s += bf2f(h[(size_t)n * KP1 + t]);
    float cnt = (float)(s1 - s0);
    out[(size_t)g * EMBD + t] = s / fmaxf(cnt, 1.0f);
}

// ---------------- fused aggregate ----------------
#define NPB 4   // nodes per block; blockDim = NPB*80 = 320

__global__ void aggregate(const ushort_t* __restrict__ h, const float* __restrict__ ebsum,
                          const int* __restrict__ estart, const int2* __restrict__ epack,
                          const float* __restrict__ epsp,
                          ushort_t* __restrict__ aggB, int N) {
    int n = blockIdx.x * NPB + threadIdx.x / 80;
    int slot = threadIdx.x % 80;
    if (n >= N) return;
    float4 acc = make_float4(0.f, 0.f, 0.f, 0.f);
    if (slot < 75) {
        const float4* b4 = (const float4*)ebsum;
        float ce = 1.0f + *epsp;
        short4v hv = *(const short4v*)(h + (size_t)n * KP1 + slot * 4);
        acc.x = ce * bf2f((ushort_t)hv[0]);
        acc.y = ce * bf2f((ushort_t)hv[1]);
        acc.z = ce * bf2f((ushort_t)hv[2]);
        acc.w = ce * bf2f((ushort_t)hv[3]);
        int p0 = estart[n], p1 = estart[n + 1];
        for (int p = p0; p < p1; ++p) {
            int2 ep = epack[p];
            short4v xv = *(const short4v*)(h + (size_t)ep.x * KP1 + slot * 4);
            float4 ev = b4[(size_t)ep.y * 75 + slot];
            acc.x += fmaxf(bf2f((ushort_t)xv[0]) + ev.x, 0.f);
            acc.y += fmaxf(bf2f((ushort_t)xv[1]) + ev.y, 0.f);
            acc.z += fmaxf(bf2f((ushort_t)xv[2]) + ev.z, 0.f);
            acc.w += fmaxf(bf2f((ushort_t)xv[3]) + ev.w, 0.f);
        }
    }
    short4v bv4;
    bv4[0] = (short)bf16_of(acc.x);
    bv4[1] = (short)bf16_of(acc.y);
    bv4[2] = (short)bf16_of(acc.z);
    bv4[3] = (short)bf16_of(acc.w);
    *(short4v*)(aggB + (size_t)n * KP1 + slot * 4) = bv4;
}

// ---------------- MFMA GEMM: single-bf16 A and B, 128x128 tile, 2-stage LDS, XCD swizzle ----------------
#define BMg 128
#define BNg 128

__global__ __launch_bounds__(256) void gemm_as(
    const ushort_t* __restrict__ A, int KP,
    const ushort_t* __restrict__ B,
    const float* __restrict__ bias, const float* __restrict__ gg,
    const float* __restrict__ bb, const float* __restrict__ bm,
    const float* __restrict__ bv,
    int Mc, int NnReal, int relu, int nb, int mb,
    float* __restrict__ outF, int ldF,
    ushort_t* __restrict__ outB, int ldP)
{
    __shared__ ushort_t sA[2][BMg * 32];   // 2 x 8 KB
    __shared__ ushort_t sB[2][BNg * 32];   // 2 x 8 KB  (32 KB total -> 5 blocks/CU)

    // XCD-aware swizzle: same m-strip lands consecutively on one XCD
    int id = blockIdx.x;
    int hi = id / (8 * nb);
    int rem = id - hi * 8 * nb;
    int xcd = rem & 7;
    int nblk = rem >> 3;
    int mblk = hi * 8 + xcd;
    if (mblk >= mb) return;

    const int tid = threadIdx.x;
    const int lane = tid & 63;
    const int w = tid >> 6;
    const int m0 = mblk * BMg;
    const int n0 = nblk * BNg;
    const int wm = (w & 1) * 64;
    const int wn = (w >> 1) * 64;

    // DMA slots: s = row*4 + q'; q' = (q + (row>>1)) & 3 swizzle; LDS base wave-uniform.
    const ushort_t* gA[2];
    const ushort_t* gB[2];
    int lbase[2];
#pragma unroll
    for (int i = 0; i < 2; ++i) {
        int s = tid + 256 * i;
        int m = s >> 2, qp = s & 3;
        int q = (qp - (m >> 1)) & 3;
        int msrc = (m0 + m < Mc) ? (m0 + m) : (Mc - 1);
        gA[i] = A + (size_t)msrc * KP + 8 * q;
        gB[i] = B + (size_t)(n0 + m) * KP + 8 * q;   // B rows fully padded
        lbase[i] = (w * 64 + 256 * i) * 8;
    }

    f32x4 acc[4][4];
#pragma unroll
    for (int a = 0; a < 4; ++a)
#pragma unroll
        for (int b = 0; b < 4; ++b) acc[a][b] = (f32x4)(0.f);

    const int q = lane >> 4;
    const int c16 = lane & 15;
    const int kt = KP >> 5;

    // prefetch tile 0 -> stage 0
#pragma unroll
    for (int i = 0; i < 2; ++i) {
        dma16(gA[i], sA[0] + lbase[i]); gA[i] += 32;
        dma16(gB[i], sB[0] + lbase[i]); gB[i] += 32;
    }
    __syncthreads();

    for (int t = 0; t < kt; ++t) {
        int cur = t & 1, nxt = cur ^ 1;
        if (t + 1 < kt) {
#pragma unroll
            for (int i = 0; i < 2; ++i) {
                dma16(gA[i], sA[nxt] + lbase[i]); gA[i] += 32;
                dma16(gB[i], sB[nxt] + lbase[i]); gB[i] += 32;
            }
        }
        short8 av[4], bhv[4];
#pragma unroll
        for (int tt = 0; tt < 4; ++tt) {
            int m = wm + tt * 16 + c16;
            int q2 = (q + (m >> 1)) & 3;
            av[tt] = *(const short8*)(sA[cur] + m * 32 + q2 * 8);
        }
#pragma unroll
        for (int uu = 0; uu < 4; ++uu) {
            int n = wn + uu * 16 + c16;
            int q2 = (q + (n >> 1)) & 3;
            bhv[uu] = *(const short8*)(sB[cur] + n * 32 + q2 * 8);
        }
#pragma unroll
        for (int tt = 0; tt < 4; ++tt)
#pragma unroll
            for (int uu = 0; uu < 4; ++uu)
                acc[tt][uu] = __builtin_amdgcn_mfma_f32_16x16x32_bf16(av[tt], bhv[uu], acc[tt][uu], 0, 0, 0);
        __syncthreads();
    }

    // epilogue: C/D layout col=lane&15, row=q*4+r
#pragma unroll
    for (int uu = 0; uu < 4; ++uu) {
        int gn = n0 + wn + uu * 16 + c16;
        float sc = 0.f, sh = 0.f;
        if (gn < NnReal) {
            sc = gg[gn] * rsqrtf(bv[gn] + 1e-5f);
            sh = bb[gn] + (bias[gn] - bm[gn]) * sc;
        }
#pragma unroll
        for (int tt = 0; tt < 4; ++tt) {
            int rbase = m0 + wm + tt * 16 + q * 4;
#pragma unroll
            for (int r = 0; r < 4; ++r) {
                int gm = rbase + r;
                if (gm >= Mc) continue;
                float y = acc[tt][uu][r] * sc + sh;
                if (relu) y = fmaxf(y, 0.f);
                if (outF) {
                    if (gn < NnReal) outF[(size_t)gm * ldF + gn] = y;
                } else {
                    if (gn < ldP) outB[(size_t)gm * ldP + gn] = bf16_of(y);
                }
            }
        }
    }
}

// ---------------- host-side MLP ----------------

struct MlpP {
    const float *b1, *g1, *be1, *m1, *v1;
    const float *b2, *g2, *be2, *m2, *v2;
};

static void run_mlp(hipStream_t stream, const ushort_t* inB, int M,
                    const ushort_t* wh, int mlp,
                    ushort_t* tB, int CH,
                    const MlpP& W, ushort_t* outB, int relu2) {
    const ushort_t* w1 = wh + (size_t)mlp * WPER;
    const ushort_t* w2 = w1 + NP1 * KP1;
    for (int c0 = 0; c0 < M; c0 += CH) {
        int Mc = (M - c0 < CH) ? (M - c0) : CH;
        int mb = cdiv(Mc, BMg);
        int mbp = cdiv(mb, 8) * 8;
        {
            int nb = NP1 / BNg;   // 5
            gemm_as<<<nb * mbp, 256, 0, stream>>>(
                inB + (size_t)c0 * KP1, KP1, w1,
                W.b1, W.g1, W.be1, W.m1, W.v1,
                Mc, 2 * EMBD, 1, nb, mb,
                nullptr, 0, tB, KP2);
        }
        {
            int nb = NP2 / BNg;   // 3
            gemm_as<<<nb * mbp, 256, 0, stream>>>(
                tB, KP2, w2,
                W.b2, W.g2, W.be2, W.m2, W.v2,
                Mc, EMBD, relu2, nb, mb,
                nullptr, 0, outB + (size_t)c0 * KP1, KP1);
        }
    }
}

// ---------------- entry ----------------

extern "C" void kernel_launch(void* const* d_in, const int* in_sizes, int n_in,
                              void* d_out, int out_size, void* d_ws, size_t ws_size,
                              hipStream_t stream) {
    const int*   x        = (const int*)d_in[0];
    const int*   ei       = (const int*)d_in[1];
    const int*   ea       = (const int*)d_in[2];
    const int*   batch    = (const int*)d_in[3];
    const float* atom_emb = (const float*)d_in[4];
    const float* bond_emb = (const float*)d_in[5];
    const float* vn_emb   = (const float*)d_in[6];
    const float* gin_eps  = (const float*)d_in[7];
    const float* gin_W1   = (const float*)d_in[8];
    const float* gin_b1   = (const float*)d_in[9];
    const float* gin_bn1g = (const float*)d_in[10];
    const float* gin_bn1b = (const float*)d_in[11];
    const float* gin_bn1m = (const float*)d_in[12];
    const float* gin_bn1v = (const float*)d_in[13];
    const float* gin_W2   = (const float*)d_in[14];
    const float* gin_b2   = (const float*)d_in[15];
    const float* bn_g     = (const float*)d_in[16];
    const float* bn_b     = (const float*)d_in[17];
    const float* bn_m     = (const float*)d_in[18];
    const float* bn_v     = (const float*)d_in[19];
    const float* vn_W1    = (const float*)d_in[20];
    const float* vn_b1    = (const float*)d_in[21];
    const float* vn_bn1g  = (const float*)d_in[22];
    const float* vn_bn1b  = (const float*)d_in[23];
    const float* vn_bn1m  = (const float*)d_in[24];
    const float* vn_bn1v  = (const float*)d_in[25];
    const float* vn_W2    = (const float*)d_in[26];
    const float* vn_b2    = (const float*)d_in[27];
    const float* vn_bn2g  = (const float*)d_in[28];
    const float* vn_bn2b  = (const float*)d_in[29];
    const float* vn_bn2m  = (const float*)d_in[30];
    const float* vn_bn2v  = (const float*)d_in[31];

    const int N = in_sizes[3];
    const int E = in_sizes[1] / 2;
    const int NB = cdiv(N, 1024);

    // ---- workspace layout (bytes); fixed ~147 MB of the ~256 MiB budget ----
    char* base = (char*)d_ws;
    size_t off = 0;
    ushort_t* hbuf = (ushort_t*)(base + off); off += (size_t)N * KP1 * 2;    // 64 MB
    ushort_t* aggB = (ushort_t*)(base + off); off += (size_t)N * KP1 * 2;    // 64 MB
    float* vnbuf   = (float*)(base + off);    off += (size_t)GG * EMBD * 4;  // 4.9 MB
    int*   starts  = (int*)(base + off);      off += 4104 * 4;
    int*   cnt     = (int*)(base + off);      off += (size_t)N * 4;
    int*   cursor  = (int*)(base + off);      off += (size_t)N * 4;
    int*   estart  = (int*)(base + off);      off += ((size_t)N + 8) * 4;
    int*   bsum    = (int*)(base + off);      off += 1032 * 4;
    int2*  epack   = (int2*)(base + off);     off += (size_t)E * 8;          // 2 MB
    float* ebsum   = (float*)(base + off);    off += (size_t)512 * EMBD * 4; // 0.6 MB
    ushort_t* whA  = (ushort_t*)(base + off); off += (size_t)9 * WPER * 2;   // 8.1 MB
    ushort_t* vnaB = (ushort_t*)(base + off); off += (size_t)GG * KP1 * 2;   // 2.6 MB
    off = (off + 255) & ~(size_t)255;

    // adaptive chunk for tB: KP2*2 = 1280 B per row; balance if 2 chunks
    size_t avail = (ws_size > off) ? ws_size - off : 0;
    int CH = (int)(avail / (KP2 * 2));
    CH &= ~255;
    if (CH > N) CH = (N + 255) & ~255;
    else if (CH >= (N + 1) / 2) CH = (((N + 1) / 2) + 255) & ~255;   // 2 balanced chunks
    if (CH < 2048) CH = 2048;  // last resort
    ushort_t* tB = (ushort_t*)(base + off);

    const int BLK = 256;
    int ne4 = N * 75;

    // ---- one-time init ----
    find_starts<<<cdiv(GG + 1, BLK), BLK, 0, stream>>>(batch, starts, N);
    atom_encode_bf<<<cdiv(ne4, BLK), BLK, 0, stream>>>(x, atom_emb, hbuf, N);
    init_vn4<<<cdiv(GG * 75, BLK), BLK, 0, stream>>>(vn_emb, vnbuf);
    bond_combo<<<cdiv(512 * EMBD, BLK), BLK, 0, stream>>>(bond_emb, ebsum);
    conv_all<<<cdiv(9 * WPER, BLK), BLK, 0, stream>>>(gin_W1, gin_W2, vn_W1, vn_W2, whA);
    hipMemsetAsync(cnt, 0, (size_t)N * 4, stream);
    hipMemsetAsync(vnaB, 0, (size_t)GG * KP1 * 2, stream);
    ecount<<<cdiv(E, BLK), BLK, 0, stream>>>(ei, cnt, E);
    scan_part<<<NB, 256, 0, stream>>>(cnt, bsum, N);
    scan_top<<<1, 1024, 0, stream>>>(bsum, NB);
    scan_final<<<NB, 256, 0, stream>>>(cnt, bsum, estart, cursor, N, E);
    escatter<<<cdiv(E, BLK), BLK, 0, stream>>>(ei, ea, cursor, epack, E);

    for (int l = 0; l < NLAY; ++l) {
        int last = (l == NLAY - 1);

        if (!last)
            pool_prep<<<GG, 320, 0, stream>>>(hbuf, vnbuf, starts, vnaB);
        else
            prep_vn<<<cdiv(ne4, BLK), BLK, 0, stream>>>(hbuf, vnbuf, batch, N);

        aggregate<<<cdiv(N, NPB), NPB * 80, 0, stream>>>(
            hbuf, ebsum, estart, epack, gin_eps + l, aggB, N);

        MlpP Wn = { gin_b1 + (size_t)l * 2 * EMBD,
                    gin_bn1g + (size_t)l * 2 * EMBD, gin_bn1b + (size_t)l * 2 * EMBD,
                    gin_bn1m + (size_t)l * 2 * EMBD, gin_bn1v + (size_t)l * 2 * EMBD,
                    gin_b2 + (size_t)l * EMBD,
                    bn_g + (size_t)l * EMBD, bn_b + (size_t)l * EMBD,
                    bn_m + (size_t)l * EMBD, bn_v + (size_t)l * EMBD };
        run_mlp(stream, aggB, N, whA, l, tB, CH, Wn, hbuf, last ? 0 : 1);

        if (!last) {
            MlpP Wv = { vn_b1 + (size_t)l * 2 * EMBD,
                        vn_bn1g + (size_t)l * 2 * EMBD, vn_bn1b + (size_t)l * 2 * EMBD,
                        vn_bn1m + (size_t)l * 2 * EMBD, vn_bn1v + (size_t)l * 2 * EMBD,
                        vn_b2 + (size_t)l * EMBD,
                        vn_bn2g + (size_t)l * EMBD, vn_bn2b + (size_t)l * EMBD,
                        vn_bn2m + (size_t)l * EMBD, vn_bn2v + (size_t)l * EMBD };
            const ushort_t* w1 = whA + (size_t)(NLAY + l) * WPER;
            const ushort_t* w2 = w1 + NP1 * KP1;
            int mb = cdiv(GG, BMg), mbp = cdiv(mb, 8) * 8;
            gemm_as<<<(NP1 / BNg) * mbp, 256, 0, stream>>>(
                vnaB, KP1, w1,
                Wv.b1, Wv.g1, Wv.be1, Wv.m1, Wv.v1,
                GG, 2 * EMBD, 1, NP1 / BNg, mb,
                nullptr, 0, tB, KP2);
            gemm_as<<<(NP2 / BNg) * mbp, 256, 0, stream>>>(
                tB, KP2, w2,
                Wv.b2, Wv.g2, Wv.be2, Wv.m2, Wv.v2,
                GG, EMBD, 1, NP2 / BNg, mb,
                vnbuf, EMBD, nullptr, 0);
        }
    }

    pool_mean<<<GG, 320, 0, stream>>>(hbuf, starts, (float*)d_out);
}